// Round 13
// baseline (796.144 us; speedup 1.0000x reference)
//
#include <hip/hip_runtime.h>
#include <math.h>

// PolaLinearAttention, MI355X round 11 (2nd resubmit; R11/R12 benches were
// broker acquisition timeouts, no data): k5 dbuf restore + coalesced fp32
// epilogue.
// R10 post-mortem: k1 single-buffer worked (230->205us, Occ 42->60) but total
// 788->795: k5 lost its dbuf and regressed ~32us (only other change). Fixes:
//  - k5 K-loop: back to R9's T3 2-phase dbuf (STAGE next -> COMPUTE cur ->
//    vmcnt(0) -> s_barrier).
//  - k5 epilogue (f32 out): was 16 scattered 4B stores/thread (96MB stream,
//    lanes 1536B apart) -- same pathology k1 had pre-R9. Now: acc+bias -> LDS
//    [64][132] f32 (33.8KB, overlaid on dead staging dbuf) in 2 half-tile
//    passes -> 512B-contiguous float4 row stores. bf16-out path keeps old code.
//  - k1 unchanged from R10 (best: 205us, Occ 60%).
// k2/k3/k4/k4b/kx/kprep unchanged.
// Layout: intermediates channel-major T: (b*384+c)*16384 + n (bf16).
//   qsT,gT,ksT in ws; vT in d_out (dead before k5 writes); xbf in d_out[2S,4S).
// ws: flag|stats(0.6MB)|qsT,gT,ksT(151MB)|W2T,WpT(1.5MB) ~= 154MB (guarded).

#define NB 4
#define NTOK 16384
#define CDIM 384
#define NHEAD 8
#define HDIM 48
#define IMGH 128
#define IMGW 128

typedef unsigned short u16;
typedef unsigned int u32;
typedef __attribute__((ext_vector_type(8))) short bf16x8;
typedef __attribute__((ext_vector_type(4))) float f32x4;

__device__ __forceinline__ float bf2f(u16 u) {
  return __uint_as_float(((unsigned)u) << 16);
}
__device__ __forceinline__ u16 f2bf(float f) {
  unsigned u = __float_as_uint(f);
  u += 0x7FFF + ((u >> 16) & 1);   // RNE
  return (u16)(u >> 16);
}
// |v|^p, safe: never logs non-positive, never inf/NaN.
__device__ __forceinline__ float pow_mag(float r, float p) {
  if (r < 1e-20f) return 0.0f;
  return exp2f(fminf(p * log2f(r), 80.0f));
}
// dual-dtype loads for EXTERNAL tensors
__device__ __forceinline__ float ldx1(const void* p, size_t i, bool f32) {
  return f32 ? ((const float*)p)[i] : bf2f(((const u16*)p)[i]);
}
// async global->LDS 16B: LDS dest is wave-uniform base + lane*16.
__device__ __forceinline__ void gload16(u16* lds, const u16* g) {
  __builtin_amdgcn_global_load_lds(
      (const __attribute__((address_space(1))) u32*)g,
      (__attribute__((address_space(3))) u32*)lds, 16, 0, 0);
}

// ---------------- k0: dtype detector ------------------------------------------------
__global__ __launch_bounds__(256) void k0_detect(const void* __restrict__ x,
                                                 int* __restrict__ flag) {
  __shared__ int s[256];
  const u16* p = (const u16*)x;
  const int t = threadIdx.x;
  int good = 0;
#pragma unroll
  for (int i = 0; i < 16; ++i) {
    const u16 w = p[t * 16 + i];
    const int e = (w >> 7) & 0xFF;
    good += (e >= 0x60 && e <= 0x85) ? 1 : 0;   // sane bf16 exponent
  }
  s[t] = good;
  __syncthreads();
  for (int o = 128; o > 0; o >>= 1) {
    if (t < o) s[t] += s[t + o];
    __syncthreads();
  }
  if (t == 0) *flag = (s[0] >= (4096 * 4) / 5) ? 0 : 1;  // 0 = bf16, 1 = fp32
}

// ---------------- kx: one-shot x fp32 -> bf16 (only when out buffer is fp32) -------
__global__ __launch_bounds__(256) void kx_convert(const void* __restrict__ x,
                                                  const int* __restrict__ flag,
                                                  u16* __restrict__ xbf) {
  if (*flag == 0) return;                       // input already bf16
  const size_t S = (size_t)NB * NTOK * CDIM;
  const size_t tid = (size_t)blockIdx.x * 256 + threadIdx.x;
  const size_t stride = (size_t)gridDim.x * 256;
  const float4* xf = (const float4*)x;
  for (size_t i = tid; i < S / 8; i += stride) {
    const float4 a = xf[i * 2 + 0];
    const float4 b = xf[i * 2 + 1];
    *(ushort4*)(xbf + i * 8 + 0) = make_ushort4(f2bf(a.x), f2bf(a.y), f2bf(a.z), f2bf(a.w));
    *(ushort4*)(xbf + i * 8 + 4) = make_ushort4(f2bf(b.x), f2bf(b.y), f2bf(b.z), f2bf(b.w));
  }
}

// ---------------- kprep: bf16 transposed weights -----------------------------------
__global__ __launch_bounds__(256) void kprep(
    const void* __restrict__ Wqg, const void* __restrict__ Wkv,
    const void* __restrict__ Wp, const int* __restrict__ flag,
    u16* __restrict__ W2T, u16* __restrict__ WpT)
{
  const bool f32 = (*flag != 0);
  const int idx = blockIdx.x * 256 + threadIdx.x;
  if (idx < 1536 * 384) {
    const int n = idx / 384, k = idx - n * 384;
    const float v = (n < 768) ? ldx1(Wqg, (size_t)k * 768 + n, f32)
                              : ldx1(Wkv, (size_t)k * 768 + (n - 768), f32);
    W2T[idx] = f2bf(v);
  } else {
    const int j = idx - 1536 * 384;
    if (j < 384 * 384) {
      const int n = j / 384, k = j - n * 384;
      WpT[j] = f2bf(ldx1(Wp, (size_t)k * 384 + n, f32));
    }
  }
}

// ---------------- k1: MFMA GEMM x @ [Wqg|Wkv] -> qsT,gT,ksT,vT ---------------------
// 128(M tok) x 128(N ch) tile, BK=64, 8 waves (2M x 4N, each 64tok x 32ch).
// Single-buffered staging (34KB block LDS -> 4 blocks/CU); coalesced epilogue.
__global__ __launch_bounds__(512) void k1_mfma(
    const void* __restrict__ x, const u16* __restrict__ xbf,
    const u16* __restrict__ W2T,
    const void* __restrict__ pos_enc, const void* __restrict__ scale_p,
    const int* __restrict__ flag, const int conv_ok,
    u16* __restrict__ qsT, u16* __restrict__ gT, u16* __restrict__ ksT, u16* __restrict__ vT)
{
  const bool f32 = (*flag != 0);
  const bool fast = (!f32) || (conv_ok != 0);   // bf16 source available
  const u16* Asrc = f32 ? xbf : (const u16*)x;
  // 34KB union: staging A[0..8191] + B[8192..16383]; epilogue et[0..17407].
  __shared__ __align__(16) u16 smem[17408];
  u16* Asm = smem;                              // [128][64] u16, XOR-swz contents
  u16* Bsm = smem + 8192;                       // [128][64]
  const int t = threadIdx.x;
  const int bid = blockIdx.x;                   // 0..6143
  const int rm = (bid & 7) * 768 + (bid >> 3);  // XCD-contiguous remap
  const int m_idx = rm / 12;
  const int n_idx = rm - m_idx * 12;
  const int n0 = n_idx * 128;                   // 0..1535
  const int m0 = m_idx * 128;                   // 0..65535
  const int wave = t >> 6, lane = t & 63;
  const int wr = wave >> 2, wc = wave & 3;      // 2M x 4N
  const int lm = lane & 15, lq = lane >> 4;

  f32x4 acc[4][2] = {};

  // stage one 128x64 A-tile + B-tile (2+2 gload16/thread)
  auto STAGE = [&](int k0) {
#pragma unroll
    for (int i = 0; i < 2; ++i) {
      const int chunk = i * 512 + t;            // 0..1023 chunks of 8 u16
      const int row = chunk >> 3, c8 = chunk & 7;
      const int sc8 = c8 ^ (row & 7);           // source-side swizzle
      u16* lpA = &Asm[(i * 512 + wave * 64) * 8];   // wave-uniform base
      u16* lpB = &Bsm[(i * 512 + wave * 64) * 8];
      gload16(lpA, Asrc + (size_t)(m0 + row) * CDIM + k0 + sc8 * 8);
      gload16(lpB, W2T + (size_t)(n0 + row) * CDIM + k0 + sc8 * 8);
    }
  };
  auto COMPUTE = [&]() {
#pragma unroll
    for (int kh = 0; kh < 2; ++kh) {
      bf16x8 af[4], bfr[2];
#pragma unroll
      for (int r = 0; r < 4; ++r) {
        const int row = wr * 64 + r * 16 + lm;
        af[r] = *(const bf16x8*)&Asm[row * 64 + (((kh * 4 + lq) ^ (row & 7)) * 8)];
      }
#pragma unroll
      for (int cb = 0; cb < 2; ++cb) {
        const int row = wc * 32 + cb * 16 + lm;
        bfr[cb] = *(const bf16x8*)&Bsm[row * 64 + (((kh * 4 + lq) ^ (row & 7)) * 8)];
      }
#pragma unroll
      for (int r = 0; r < 4; ++r)
#pragma unroll
        for (int cb = 0; cb < 2; ++cb)
          acc[r][cb] = __builtin_amdgcn_mfma_f32_16x16x32_bf16(af[r], bfr[cb], acc[r][cb], 0, 0, 0);
    }
  };

  if (fast) {
    for (int ks = 0; ks < 6; ++ks) {
      STAGE(ks * 64);
      __syncthreads();                          // drains vmcnt -> tile landed
      COMPUTE();
      __syncthreads();                          // reads done before next STAGE
    }
  } else {
    // fallback: fp32 input but no bf16 scratch (out buffer too small)
    for (int k0 = 0; k0 < CDIM; k0 += 64) {
#pragma unroll
      for (int i = 0; i < 2; ++i) {
        const int chunk = t + i * 512;
        const int row = chunk >> 3, c8 = chunk & 7;
        const int ldsoff = row * 64 + ((c8 ^ (row & 7)) * 8);
        const float* xp = (const float*)x + (size_t)(m0 + row) * CDIM + k0 + c8 * 8;
        const float4 v0 = *(const float4*)xp;
        const float4 v1 = *(const float4*)(xp + 4);
        *(ushort4*)&Asm[ldsoff]     = make_ushort4(f2bf(v0.x), f2bf(v0.y), f2bf(v0.z), f2bf(v0.w));
        *(ushort4*)&Asm[ldsoff + 4] = make_ushort4(f2bf(v1.x), f2bf(v1.y), f2bf(v1.z), f2bf(v1.w));
        *(uint4*)&Bsm[ldsoff] = *(const uint4*)(W2T + (size_t)(n0 + row) * CDIM + k0 + c8 * 8);
      }
      __syncthreads();
      COMPUTE();
      __syncthreads();
    }
  }

  // ---- epilogue: regs -> LDS [128ch][136] u16 -> coalesced 16B stores ----
  u16* et = smem;                               // 128 x 136 u16 = 34KB
  const int b = m0 >> 14;
  const int TOK0 = m0 & (NTOK - 1);
  const int region = n0 / CDIM;                 // uniform per block (384 = 3*128)
#pragma unroll
  for (int cb = 0; cb < 2; ++cb) {
    const int cl = wc * 32 + cb * 16 + lm;      // local channel 0..127
    const int c = (n0 - region * CDIM) + cl;    // 0..383
    float inv = 1.0f;
    if (region == 0 || region == 2) inv = 1.0f / log1pf(expf(ldx1(scale_p, c, f32)));
#pragma unroll
    for (int r = 0; r < 4; ++r) {
      const int tl = wr * 64 + r * 16 + lq * 4; // local token 0..127
      const f32x4 v = acc[r][cb];
      ushort4 w;
      if (region == 2) {
        const int tok = TOK0 + tl;
        const float p0 = ldx1(pos_enc, (size_t)(tok + 0) * CDIM + c, f32);
        const float p1 = ldx1(pos_enc, (size_t)(tok + 1) * CDIM + c, f32);
        const float p2 = ldx1(pos_enc, (size_t)(tok + 2) * CDIM + c, f32);
        const float p3 = ldx1(pos_enc, (size_t)(tok + 3) * CDIM + c, f32);
        w = make_ushort4(f2bf((v[0] + p0) * inv), f2bf((v[1] + p1) * inv),
                         f2bf((v[2] + p2) * inv), f2bf((v[3] + p3) * inv));
      } else if (region == 0) {
        w = make_ushort4(f2bf(v[0] * inv), f2bf(v[1] * inv), f2bf(v[2] * inv), f2bf(v[3] * inv));
      } else {
        w = make_ushort4(f2bf(v[0]), f2bf(v[1]), f2bf(v[2]), f2bf(v[3]));
      }
      *(ushort4*)&et[cl * 136 + tl] = w;
    }
  }
  __syncthreads();
  u16* dst = (region == 0) ? qsT : (region == 1) ? gT : (region == 2) ? ksT : vT;
  const int cbase = b * CDIM + (n0 - region * CDIM);
#pragma unroll
  for (int i = 0; i < 4; ++i) {
    const int idx = i * 512 + t;
    const int row = idx >> 4, seg = idx & 15;   // row = channel, seg = 16B chunk
    const uint4 val = *(const uint4*)&et[row * 136 + seg * 8];
    *(uint4*)(dst + ((size_t)(cbase + row)) * NTOK + TOK0 + seg * 8) = val;
  }
}

// ---------------- k2: per (b,h): km[96] = mean(kk), kvm[96][48] = kk^T v / N -------
__global__ __launch_bounds__(256) void k2_stats(
    const u16* __restrict__ ksT, const u16* __restrict__ vT,
    const void* __restrict__ power_p, const int* __restrict__ flag,
    float* __restrict__ km, float* __restrict__ kvm)
{
  const bool f32 = (*flag != 0);
  __shared__ float kkL[96][65];
  __shared__ float vL[48][65];
  __shared__ float pw[48];
  const int bh = blockIdx.x;
  const int b = bh >> 3, h = bh & 7;
  const int t = threadIdx.x;
  if (t < 48) pw[t] = 1.0f + 4.0f / (1.0f + expf(-ldx1(power_p, h * HDIM + t, f32)));
  __syncthreads();
  const int td = t & 15, te = t >> 4;
  float acc[6][3] = {};
  float ksum = 0.0f;
  const u16* ksbase = ksT + ((size_t)(b * CDIM + h * HDIM)) * NTOK;
  const u16* vbase  = vT  + ((size_t)(b * CDIM + h * HDIM)) * NTOK;
  const int n0base = blockIdx.y * 1024;
  for (int tile = 0; tile < 16; ++tile) {
    const int n0 = n0base + tile * 64;
    for (int i = t; i < 48 * 16; i += 256) {
      const int c = i >> 4, qd = (i & 15) * 4;
      ushort4 kq = *(const ushort4*)(ksbase + (size_t)c * NTOK + n0 + qd);
      ushort4 vq = *(const ushort4*)(vbase  + (size_t)c * NTOK + n0 + qd);
      const float p = pw[c];
      float kf[4] = {bf2f(kq.x), bf2f(kq.y), bf2f(kq.z), bf2f(kq.w)};
      float vf[4] = {bf2f(vq.x), bf2f(vq.y), bf2f(vq.z), bf2f(vq.w)};
#pragma unroll
      for (int jj = 0; jj < 4; ++jj) {
        const float f = pow_mag(fabsf(kf[jj]), p);
        kkL[c][qd + jj]      = (kf[jj] > 0.f) ? f : 0.f;
        kkL[c + 48][qd + jj] = (kf[jj] < 0.f) ? f : 0.f;
        vL[c][qd + jj] = vf[jj];
      }
    }
    __syncthreads();
#pragma unroll 2
    for (int nn = 0; nn < 64; ++nn) {
      float av[6], bv[3];
#pragma unroll
      for (int i = 0; i < 6; ++i) av[i] = kkL[td * 6 + i][nn];
#pragma unroll
      for (int j = 0; j < 3; ++j) bv[j] = vL[te * 3 + j][nn];
#pragma unroll
      for (int i = 0; i < 6; ++i)
#pragma unroll
        for (int j = 0; j < 3; ++j)
          acc[i][j] = fmaf(av[i], bv[j], acc[i][j]);
    }
    if (t < 96) {
#pragma unroll 4
      for (int nn = 0; nn < 64; ++nn) ksum += kkL[t][nn];
    }
    __syncthreads();
  }
  const float inv_n = 1.0f / (float)NTOK;
#pragma unroll
  for (int i = 0; i < 6; ++i)
#pragma unroll
    for (int j = 0; j < 3; ++j)
      atomicAdd(&kvm[(size_t)bh * 96 * 48 + (td * 6 + i) * 48 + (te * 3 + j)], acc[i][j] * inv_n);
  if (t < 96) atomicAdd(&km[bh * 96 + t], ksum * inv_n);
}

// ---------------- k3: q features, z-norm, x_sim/x_opp; attn -> ksT -----------------
__global__ __launch_bounds__(256) void k3_attn(
    const u16* __restrict__ qsT, u16* __restrict__ attnT,
    const float* __restrict__ km_g, const float* __restrict__ kvm_g,
    const void* __restrict__ power_p, const int* __restrict__ flag)
{
  const bool f32 = (*flag != 0);
  __shared__ __align__(16) float kvmL[96][48];
  __shared__ float kmL[96];
  __shared__ float pw[48];
  const int bh = blockIdx.y;
  const int b = bh >> 3, h = bh & 7;
  const int t = threadIdx.x;
  for (int i = t; i < 96 * 48; i += 256) kvmL[i / 48][i % 48] = kvm_g[(size_t)bh * 96 * 48 + i];
  if (t < 96) kmL[t] = km_g[bh * 96 + t];
  if (t < 48) pw[t] = 1.0f + 4.0f / (1.0f + expf(-ldx1(power_p, h * HDIM + t, f32)));
  __syncthreads();
  const int n = blockIdx.x * 512 + t;
  const size_t chan0 = ((size_t)(b * CDIM + h * HDIM)) * NTOK + n;
  const u16* qbase = qsT + chan0;
  u16* obase = attnT + chan0;
  float4 accs[2][6] = {}, acco[2][6] = {};
  float zs[2] = {}, zo[2] = {};
  for (int d = 0; d < 48; ++d) {
    const float p = pw[d];
    float qp[2], qn[2];
#pragma unroll
    for (int i = 0; i < 2; ++i) {
      const float qv = bf2f(qbase[(size_t)d * NTOK + i * 256]);
      const float f = pow_mag(fabsf(qv), p);
      qp[i] = (qv > 0.f) ? f : 0.f;
      qn[i] = (qv < 0.f) ? f : 0.f;
      zs[i] = fmaf(qp[i], kmL[d], zs[i]); zs[i] = fmaf(qn[i], kmL[d + 48], zs[i]);
      zo[i] = fmaf(qn[i], kmL[d], zo[i]); zo[i] = fmaf(qp[i], kmL[d + 48], zo[i]);
    }
#pragma unroll
    for (int e4 = 0; e4 < 6; ++e4) {
      const float4 kvA = *(const float4*)&kvmL[d][e4 * 4];
      const float4 kvB = *(const float4*)&kvmL[d + 48][e4 * 4];
      const float4 kvC = *(const float4*)&kvmL[d][24 + e4 * 4];
      const float4 kvD = *(const float4*)&kvmL[d + 48][24 + e4 * 4];
#pragma unroll
      for (int i = 0; i < 2; ++i) {
        accs[i][e4].x = fmaf(qp[i], kvA.x, fmaf(qn[i], kvB.x, accs[i][e4].x));
        accs[i][e4].y = fmaf(qp[i], kvA.y, fmaf(qn[i], kvB.y, accs[i][e4].y));
        accs[i][e4].z = fmaf(qp[i], kvA.z, fmaf(qn[i], kvB.z, accs[i][e4].z));
        accs[i][e4].w = fmaf(qp[i], kvA.w, fmaf(qn[i], kvB.w, accs[i][e4].w));
        acco[i][e4].x = fmaf(qn[i], kvC.x, fmaf(qp[i], kvD.x, acco[i][e4].x));
        acco[i][e4].y = fmaf(qn[i], kvC.y, fmaf(qp[i], kvD.y, acco[i][e4].y));
        acco[i][e4].z = fmaf(qn[i], kvC.z, fmaf(qp[i], kvD.z, acco[i][e4].z));
        acco[i][e4].w = fmaf(qn[i], kvC.w, fmaf(qp[i], kvD.w, acco[i][e4].w));
      }
    }
  }
#pragma unroll
  for (int i = 0; i < 2; ++i) {
    const float zsi = 1.0f / (zs[i] + 1e-6f);
    const float zoi = 1.0f / (zo[i] + 1e-6f);
#pragma unroll
    for (int e4 = 0; e4 < 6; ++e4) {
      const float4 s = accs[i][e4], o = acco[i][e4];
      obase[(size_t)(e4 * 4 + 0) * NTOK + i * 256]    = f2bf(s.x * zsi);
      obase[(size_t)(e4 * 4 + 1) * NTOK + i * 256]    = f2bf(s.y * zsi);
      obase[(size_t)(e4 * 4 + 2) * NTOK + i * 256]    = f2bf(s.z * zsi);
      obase[(size_t)(e4 * 4 + 3) * NTOK + i * 256]    = f2bf(s.w * zsi);
      obase[(size_t)(24 + e4 * 4 + 0) * NTOK + i * 256] = f2bf(o.x * zoi);
      obase[(size_t)(24 + e4 * 4 + 1) * NTOK + i * 256] = f2bf(o.y * zoi);
      obase[(size_t)(24 + e4 * 4 + 2) * NTOK + i * 256] = f2bf(o.z * zoi);
      obase[(size_t)(24 + e4 * 4 + 3) * NTOK + i * 256] = f2bf(o.w * zoi);
    }
  }
}

// ---------------- k4: 5x5 depthwise conv on vT + out2 = (attn + conv) * g ----------
__global__ __launch_bounds__(256) void k4_conv_combine(
    const u16* __restrict__ vT, const u16* __restrict__ gT,
    const void* __restrict__ dwc_w, const void* __restrict__ dwc_b,
    const int* __restrict__ flag,
    u16* __restrict__ attnT)
{
  const bool f32 = (*flag != 0);
  __shared__ float tile[20][128];
  const int bc = blockIdx.y;
  const int y0 = blockIdx.x * 16;
  const int t = threadIdx.x;
  const int d = bc % 48;
  float w[25];
#pragma unroll
  for (int i = 0; i < 25; ++i) w[i] = ldx1(dwc_w, d * 25 + i, f32);
  const float bias = ldx1(dwc_b, d, f32);
  const u16* vimg = vT + (size_t)bc * NTOK;
  for (int i = t; i < 20 * 128; i += 256) {
    const int r = i >> 7, xx = i & 127;
    const int gy = y0 + r - 2;
    tile[r][xx] = (gy >= 0 && gy < IMGH) ? bf2f(vimg[gy * IMGW + xx]) : 0.f;
  }
  __syncthreads();
  u16* abase = attnT + (size_t)bc * NTOK;
  const u16* gbase = gT + (size_t)bc * NTOK;
#pragma unroll
  for (int k = 0; k < 8; ++k) {
    const int px = t + k * 256;
    const int yy = px >> 7, xcol = px & 127;
    float acc = bias;
#pragma unroll
    for (int dy = 0; dy < 5; ++dy)
#pragma unroll
      for (int dx = 0; dx < 5; ++dx) {
        const int ux = xcol + dx - 2;
        const float val = (ux >= 0 && ux < IMGW) ? tile[yy + dy][ux] : 0.f;
        acc = fmaf(w[dy * 5 + dx], val, acc);
      }
    const int gidx = (y0 + yy) * IMGW + xcol;
    abase[gidx] = f2bf((bf2f(abase[gidx]) + acc) * bf2f(gbase[gidx]));
  }
}

// ---------------- k4b: transpose out2 channel-major -> token-major -----------------
__global__ __launch_bounds__(256) void k4b_transpose(
    const u16* __restrict__ src,   // [(b*384+c)][n]
    u16* __restrict__ dst)         // [(b*16384+n)][c]
{
  __shared__ u16 tile[64][68];
  const int b  = blockIdx.z;
  const int c0 = blockIdx.y * 64;
  const int n0 = blockIdx.x * 64;
  const int t = threadIdx.x;
  const int tr = t >> 4, tq = t & 15;
#pragma unroll
  for (int i = 0; i < 4; ++i) {
    const int r = tr + i * 16;     // c-row
    *(ushort4*)&tile[r][tq * 4] =
        *(const ushort4*)(src + ((size_t)(b * CDIM + c0 + r)) * NTOK + n0 + tq * 4);
  }
  __syncthreads();
#pragma unroll
  for (int i = 0; i < 4; ++i) {
    const int n = tr + i * 16;     // token-row
    const ushort4 vv = make_ushort4(tile[tq * 4 + 0][n], tile[tq * 4 + 1][n],
                                    tile[tq * 4 + 2][n], tile[tq * 4 + 3][n]);
    *(ushort4*)(dst + ((size_t)(b * NTOK + n0 + n)) * CDIM + c0 + tq * 4) = vv;
  }
}

// ---------------- k5: MFMA GEMM out2_tm @ Wproj + b -> d_out -----------------------
// T3 2-phase dbuf K-loop (R9); NEW: coalesced fp32 epilogue via LDS (2 passes).
__global__ __launch_bounds__(256) void k5_mfma(
    const u16* __restrict__ A,     // [row=b*16384+n][c] bf16
    const u16* __restrict__ WpT,   // [c_out][c_in] bf16
    const void* __restrict__ bp, const int* __restrict__ flag,
    void* __restrict__ out)
{
  const bool f32 = (*flag != 0);
  // flat 64KB: A dbuf [0..16384), B dbuf [16384..32768) u16.
  // epilogue overlays first 33.8KB as float ef[64][132].
  __shared__ __align__(16) u16 smem[32768];
  u16* Asm0 = smem;
  u16* Asm1 = smem + 8192;
  u16* Bsm0 = smem + 16384;
  u16* Bsm1 = smem + 24576;
  const int t = threadIdx.x;
  const int bid = blockIdx.x;                   // 0..1535
  const int rm = (bid & 7) * 192 + (bid >> 3);  // XCD-contiguous remap
  const int m_idx = rm / 3;
  const int n_idx = rm - m_idx * 3;
  const int n0 = n_idx * 128;                   // 0..383
  const int m0 = m_idx * 128;
  const int wave = t >> 6, lane = t & 63;
  const int wr = wave >> 1, wc = wave & 1;
  const int lm = lane & 15, lq = lane >> 4;

  f32x4 acc[4][4] = {};

  auto STAGE = [&](int buf, int k0) {
    u16* Ab = buf ? Asm1 : Asm0;
    u16* Bb = buf ? Bsm1 : Bsm0;
#pragma unroll
    for (int i = 0; i < 4; ++i) {
      const int chunk = i * 256 + t;
      const int row = chunk >> 3, c8 = chunk & 7;
      const int sc8 = c8 ^ (row & 7);           // source-side swizzle
      u16* lpA = &Ab[(i * 256 + wave * 64) * 8];
      u16* lpB = &Bb[(i * 256 + wave * 64) * 8];
      gload16(lpA, A + (size_t)(m0 + row) * CDIM + k0 + sc8 * 8);
      gload16(lpB, WpT + (size_t)(n0 + row) * CDIM + k0 + sc8 * 8);
    }
  };
  auto COMPUTE = [&](int buf) {
    u16* Ab = buf ? Asm1 : Asm0;
    u16* Bb = buf ? Bsm1 : Bsm0;
#pragma unroll
    for (int kh = 0; kh < 2; ++kh) {
      bf16x8 af[4], bfr[4];
#pragma unroll
      for (int r = 0; r < 4; ++r) {
        const int row = wr * 64 + r * 16 + lm;
        af[r] = *(const bf16x8*)&Ab[row * 64 + (((kh * 4 + lq) ^ (row & 7)) * 8)];
      }
#pragma unroll
      for (int cb = 0; cb < 4; ++cb) {
        const int row = wc * 64 + cb * 16 + lm;
        bfr[cb] = *(const bf16x8*)&Bb[row * 64 + (((kh * 4 + lq) ^ (row & 7)) * 8)];
      }
#pragma unroll
      for (int r = 0; r < 4; ++r)
#pragma unroll
        for (int cb = 0; cb < 4; ++cb)
          acc[r][cb] = __builtin_amdgcn_mfma_f32_16x16x32_bf16(af[r], bfr[cb], acc[r][cb], 0, 0, 0);
    }
  };

  STAGE(0, 0);
  asm volatile("s_waitcnt vmcnt(0)" ::: "memory");
  __builtin_amdgcn_sched_barrier(0);
  __builtin_amdgcn_s_barrier();
  int cur = 0;
#pragma unroll
  for (int ks = 0; ks < 5; ++ks) {
    STAGE(cur ^ 1, (ks + 1) * 64);
    COMPUTE(cur);
    asm volatile("s_waitcnt vmcnt(0)" ::: "memory");
    __builtin_amdgcn_sched_barrier(0);
    __builtin_amdgcn_s_barrier();
    cur ^= 1;
  }
  COMPUTE(cur);

  if (f32) {
    // ---- coalesced fp32 epilogue: 2 half-tile passes through LDS ----
    float* ef = (float*)smem;                   // 64 x 132 f32 = 33.8KB
    float bb[4];
#pragma unroll
    for (int cb = 0; cb < 4; ++cb) bb[cb] = ((const float*)bp)[n0 + wc * 64 + cb * 16 + lm];
    for (int h = 0; h < 2; ++h) {
      __syncthreads();                          // K-loop reads / prev pass done
      if (wr == h) {
#pragma unroll
        for (int cb = 0; cb < 4; ++cb) {
          const int cl = wc * 64 + cb * 16 + lm;    // 0..127
#pragma unroll
          for (int r = 0; r < 4; ++r) {
            const int tl = r * 16 + lq * 4;         // 0..63 in half-tile
            const f32x4 v = acc[r][cb];
#pragma unroll
            for (int reg = 0; reg < 4; ++reg)
              ef[(tl + reg) * 132 + cl] = v[reg] + bb[cb];
          }
        }
      }
      __syncthreads();
      // store 64 rows x 128 c: 512B contiguous per row
      float* ob = (float*)out + (size_t)(m0 + h * 64) * CDIM + n0;
#pragma unroll
      for (int i = 0; i < 8; ++i) {
        const int idx = i * 256 + t;
        const int row = idx >> 5, seg = idx & 31; // 32 x float4 per row
        const float4 val = *(const float4*)&ef[row * 132 + seg * 4];
        *(float4*)(ob + (size_t)row * CDIM + seg * 4) = val;
      }
    }
  } else {
    // bf16 out: original scattered path (rare)
#pragma unroll
    for (int cb = 0; cb < 4; ++cb) {
      const int cg = n0 + wc * 64 + cb * 16 + lm;
      const float bbs = bf2f(((const u16*)bp)[cg]);
#pragma unroll
      for (int r = 0; r < 4; ++r) {
        const int rowtok = m0 + wr * 64 + r * 16 + lq * 4;
        const f32x4 v = acc[r][cb];
#pragma unroll
        for (int reg = 0; reg < 4; ++reg) {
          const size_t o = (size_t)(rowtok + reg) * CDIM + cg;
          ((u16*)out)[o] = f2bf(v[reg] + bbs);
        }
      }
    }
  }
}

extern "C" void kernel_launch(void* const* d_in, const int* in_sizes, int n_in,
                              void* d_out, int out_size, void* d_ws, size_t ws_size,
                              hipStream_t stream) {
  const void* x       = d_in[0];
  const void* Wqg     = d_in[1];
  const void* Wkv     = d_in[2];
  const void* Wproj   = d_in[3];
  const void* bproj   = d_in[4];
  const void* pos_enc = d_in[5];
  const void* power_p = d_in[6];
  const void* scale_p = d_in[7];
  const void* dwc_w   = d_in[8];
  const void* dwc_b   = d_in[9];

  const size_t S = (size_t)NB * NTOK * CDIM;                 // 25,165,824
  const size_t stats_off   = 256;
  const size_t stats_bytes = (size_t)(32 * 96 + 32 * 96 * 48) * sizeof(float);
  const size_t w2t_elems = 1536 * 384, wpt_elems = 384 * 384;
  const size_t need = stats_off + stats_bytes + 3 * S * sizeof(u16)
                    + (w2t_elems + wpt_elems) * sizeof(u16);
  if (ws_size < need) return;

  int*   flag = (int*)d_ws;
  float* km   = (float*)((char*)d_ws + stats_off);
  float* kvm  = km + 32 * 96;
  u16* qsT = (u16*)((char*)d_ws + stats_off + stats_bytes);  // q/scale; later out2_tm
  u16* gT  = qsT + S;
  u16* ksT = gT + S;                                         // k feats; attn; out2
  u16* W2T = ksT + S;
  u16* WpT = W2T + w2t_elems;
  u16* vT  = (u16*)d_out;                                    // dead before k5 writes

  // bf16 scratch for x lives in the SECOND half of d_out when out is fp32
  // (bytes [2S, 4S) -- disjoint from vT's [0, 2S); dead once k1 completes,
  // k5 overwrites the whole out buffer afterwards).
  const int conv_ok = (out_size >= (int)(S * 4)) ? 1 : 0;
  u16* xbf = conv_ok ? ((u16*)d_out + S) : (u16*)d_out;      // unused if !conv_ok

  hipMemsetAsync(km, 0, stats_bytes, stream);

  k0_detect<<<1, 256, 0, stream>>>(x, flag);
  if (conv_ok) kx_convert<<<2048, 256, 0, stream>>>(x, flag, xbf);
  kprep<<<(int)((w2t_elems + wpt_elems + 255) / 256), 256, 0, stream>>>(
      Wqg, Wkv, Wproj, flag, W2T, WpT);
  k1_mfma<<<6144, 512, 0, stream>>>(x, xbf, W2T, pos_enc, scale_p, flag, conv_ok,
                                    qsT, gT, ksT, vT);
  k2_stats<<<dim3(32, 16), 256, 0, stream>>>(ksT, vT, power_p, flag, km, kvm);
  k3_attn<<<dim3(32, 32), 256, 0, stream>>>(qsT, ksT, km, kvm, power_p, flag);
  k4_conv_combine<<<dim3(8, 1536), 256, 0, stream>>>(vT, gT, dwc_w, dwc_b, flag, ksT);
  k4b_transpose<<<dim3(256, 6, 4), 256, 0, stream>>>(ksT, qsT);
  k5_mfma<<<1536, 256, 0, stream>>>(qsT, WpT, bproj, flag, d_out);
}

// Round 14
// 756.742 us; speedup vs baseline: 1.0521x; 1.0521x over previous
//
#include <hip/hip_runtime.h>
#include <math.h>

// PolaLinearAttention, MI355X round 14: vectorize the mid-section's scalar LDS.
// R13 post-mortem: k5 dbuf+coalesced-epilogue = neutral vs R10 (796 vs 795);
// k1 fixed at 205us. Remaining ~560us is the unprofiled mid-section. Instr
// arithmetic: k2's MAC loop = 9 scalar ds_read_b32/nn (stride-65 col reads,
// 4-way conflicted) x 64nn x 16 tiles x 8 waves/CU ~ 270us ceiling; k4 = 200
// scalar tile reads + 200 bound-selects/thread ~ 90us. Fixes (same theory x2):
//  - k2: pad 65->68, nn-unroll-4, float4 av/bv reads (9 b128 per 4nn vs 36
//    b32), float4 fill writes, vectorized ksum. Math identical (f32 FMA).
//  - k4: halo baked into LDS tile [20][136] (zero-padded), 4 outputs/thread
//    via 3 aligned float4 row reads + register-shifted 5-tap stencil,
//    ushort4 RMW writeback. Math identical.
// k1 (205us, Occ 60) / k3 / k4b / k5 (R13 parity) untouched -> k1 = control.
// Layout: intermediates channel-major T: (b*384+c)*16384 + n (bf16).
//   qsT,gT,ksT in ws; vT in d_out (dead before k5 writes); xbf in d_out[2S,4S).
// ws: flag|stats(0.6MB)|qsT,gT,ksT(151MB)|W2T,WpT(1.5MB) ~= 154MB (guarded).

#define NB 4
#define NTOK 16384
#define CDIM 384
#define NHEAD 8
#define HDIM 48
#define IMGH 128
#define IMGW 128

typedef unsigned short u16;
typedef unsigned int u32;
typedef __attribute__((ext_vector_type(8))) short bf16x8;
typedef __attribute__((ext_vector_type(4))) float f32x4;

__device__ __forceinline__ float bf2f(u16 u) {
  return __uint_as_float(((unsigned)u) << 16);
}
__device__ __forceinline__ u16 f2bf(float f) {
  unsigned u = __float_as_uint(f);
  u += 0x7FFF + ((u >> 16) & 1);   // RNE
  return (u16)(u >> 16);
}
// |v|^p, safe: never logs non-positive, never inf/NaN.
__device__ __forceinline__ float pow_mag(float r, float p) {
  if (r < 1e-20f) return 0.0f;
  return exp2f(fminf(p * log2f(r), 80.0f));
}
// dual-dtype loads for EXTERNAL tensors
__device__ __forceinline__ float ldx1(const void* p, size_t i, bool f32) {
  return f32 ? ((const float*)p)[i] : bf2f(((const u16*)p)[i]);
}
// async global->LDS 16B: LDS dest is wave-uniform base + lane*16.
__device__ __forceinline__ void gload16(u16* lds, const u16* g) {
  __builtin_amdgcn_global_load_lds(
      (const __attribute__((address_space(1))) u32*)g,
      (__attribute__((address_space(3))) u32*)lds, 16, 0, 0);
}

// ---------------- k0: dtype detector ------------------------------------------------
__global__ __launch_bounds__(256) void k0_detect(const void* __restrict__ x,
                                                 int* __restrict__ flag) {
  __shared__ int s[256];
  const u16* p = (const u16*)x;
  const int t = threadIdx.x;
  int good = 0;
#pragma unroll
  for (int i = 0; i < 16; ++i) {
    const u16 w = p[t * 16 + i];
    const int e = (w >> 7) & 0xFF;
    good += (e >= 0x60 && e <= 0x85) ? 1 : 0;   // sane bf16 exponent
  }
  s[t] = good;
  __syncthreads();
  for (int o = 128; o > 0; o >>= 1) {
    if (t < o) s[t] += s[t + o];
    __syncthreads();
  }
  if (t == 0) *flag = (s[0] >= (4096 * 4) / 5) ? 0 : 1;  // 0 = bf16, 1 = fp32
}

// ---------------- kx: one-shot x fp32 -> bf16 (only when out buffer is fp32) -------
__global__ __launch_bounds__(256) void kx_convert(const void* __restrict__ x,
                                                  const int* __restrict__ flag,
                                                  u16* __restrict__ xbf) {
  if (*flag == 0) return;                       // input already bf16
  const size_t S = (size_t)NB * NTOK * CDIM;
  const size_t tid = (size_t)blockIdx.x * 256 + threadIdx.x;
  const size_t stride = (size_t)gridDim.x * 256;
  const float4* xf = (const float4*)x;
  for (size_t i = tid; i < S / 8; i += stride) {
    const float4 a = xf[i * 2 + 0];
    const float4 b = xf[i * 2 + 1];
    *(ushort4*)(xbf + i * 8 + 0) = make_ushort4(f2bf(a.x), f2bf(a.y), f2bf(a.z), f2bf(a.w));
    *(ushort4*)(xbf + i * 8 + 4) = make_ushort4(f2bf(b.x), f2bf(b.y), f2bf(b.z), f2bf(b.w));
  }
}

// ---------------- kprep: bf16 transposed weights -----------------------------------
__global__ __launch_bounds__(256) void kprep(
    const void* __restrict__ Wqg, const void* __restrict__ Wkv,
    const void* __restrict__ Wp, const int* __restrict__ flag,
    u16* __restrict__ W2T, u16* __restrict__ WpT)
{
  const bool f32 = (*flag != 0);
  const int idx = blockIdx.x * 256 + threadIdx.x;
  if (idx < 1536 * 384) {
    const int n = idx / 384, k = idx - n * 384;
    const float v = (n < 768) ? ldx1(Wqg, (size_t)k * 768 + n, f32)
                              : ldx1(Wkv, (size_t)k * 768 + (n - 768), f32);
    W2T[idx] = f2bf(v);
  } else {
    const int j = idx - 1536 * 384;
    if (j < 384 * 384) {
      const int n = j / 384, k = j - n * 384;
      WpT[j] = f2bf(ldx1(Wp, (size_t)k * 384 + n, f32));
    }
  }
}

// ---------------- k1: MFMA GEMM x @ [Wqg|Wkv] -> qsT,gT,ksT,vT ---------------------
// 128(M tok) x 128(N ch) tile, BK=64, 8 waves (2M x 4N, each 64tok x 32ch).
// Single-buffered staging (34KB block LDS -> 4 blocks/CU); coalesced epilogue.
__global__ __launch_bounds__(512) void k1_mfma(
    const void* __restrict__ x, const u16* __restrict__ xbf,
    const u16* __restrict__ W2T,
    const void* __restrict__ pos_enc, const void* __restrict__ scale_p,
    const int* __restrict__ flag, const int conv_ok,
    u16* __restrict__ qsT, u16* __restrict__ gT, u16* __restrict__ ksT, u16* __restrict__ vT)
{
  const bool f32 = (*flag != 0);
  const bool fast = (!f32) || (conv_ok != 0);   // bf16 source available
  const u16* Asrc = f32 ? xbf : (const u16*)x;
  // 34KB union: staging A[0..8191] + B[8192..16383]; epilogue et[0..17407].
  __shared__ __align__(16) u16 smem[17408];
  u16* Asm = smem;                              // [128][64] u16, XOR-swz contents
  u16* Bsm = smem + 8192;                       // [128][64]
  const int t = threadIdx.x;
  const int bid = blockIdx.x;                   // 0..6143
  const int rm = (bid & 7) * 768 + (bid >> 3);  // XCD-contiguous remap
  const int m_idx = rm / 12;
  const int n_idx = rm - m_idx * 12;
  const int n0 = n_idx * 128;                   // 0..1535
  const int m0 = m_idx * 128;                   // 0..65535
  const int wave = t >> 6, lane = t & 63;
  const int wr = wave >> 2, wc = wave & 3;      // 2M x 4N
  const int lm = lane & 15, lq = lane >> 4;

  f32x4 acc[4][2] = {};

  // stage one 128x64 A-tile + B-tile (2+2 gload16/thread)
  auto STAGE = [&](int k0) {
#pragma unroll
    for (int i = 0; i < 2; ++i) {
      const int chunk = i * 512 + t;            // 0..1023 chunks of 8 u16
      const int row = chunk >> 3, c8 = chunk & 7;
      const int sc8 = c8 ^ (row & 7);           // source-side swizzle
      u16* lpA = &Asm[(i * 512 + wave * 64) * 8];   // wave-uniform base
      u16* lpB = &Bsm[(i * 512 + wave * 64) * 8];
      gload16(lpA, Asrc + (size_t)(m0 + row) * CDIM + k0 + sc8 * 8);
      gload16(lpB, W2T + (size_t)(n0 + row) * CDIM + k0 + sc8 * 8);
    }
  };
  auto COMPUTE = [&]() {
#pragma unroll
    for (int kh = 0; kh < 2; ++kh) {
      bf16x8 af[4], bfr[2];
#pragma unroll
      for (int r = 0; r < 4; ++r) {
        const int row = wr * 64 + r * 16 + lm;
        af[r] = *(const bf16x8*)&Asm[row * 64 + (((kh * 4 + lq) ^ (row & 7)) * 8)];
      }
#pragma unroll
      for (int cb = 0; cb < 2; ++cb) {
        const int row = wc * 32 + cb * 16 + lm;
        bfr[cb] = *(const bf16x8*)&Bsm[row * 64 + (((kh * 4 + lq) ^ (row & 7)) * 8)];
      }
#pragma unroll
      for (int r = 0; r < 4; ++r)
#pragma unroll
        for (int cb = 0; cb < 2; ++cb)
          acc[r][cb] = __builtin_amdgcn_mfma_f32_16x16x32_bf16(af[r], bfr[cb], acc[r][cb], 0, 0, 0);
    }
  };

  if (fast) {
    for (int ks = 0; ks < 6; ++ks) {
      STAGE(ks * 64);
      __syncthreads();                          // drains vmcnt -> tile landed
      COMPUTE();
      __syncthreads();                          // reads done before next STAGE
    }
  } else {
    // fallback: fp32 input but no bf16 scratch (out buffer too small)
    for (int k0 = 0; k0 < CDIM; k0 += 64) {
#pragma unroll
      for (int i = 0; i < 2; ++i) {
        const int chunk = t + i * 512;
        const int row = chunk >> 3, c8 = chunk & 7;
        const int ldsoff = row * 64 + ((c8 ^ (row & 7)) * 8);
        const float* xp = (const float*)x + (size_t)(m0 + row) * CDIM + k0 + c8 * 8;
        const float4 v0 = *(const float4*)xp;
        const float4 v1 = *(const float4*)(xp + 4);
        *(ushort4*)&Asm[ldsoff]     = make_ushort4(f2bf(v0.x), f2bf(v0.y), f2bf(v0.z), f2bf(v0.w));
        *(ushort4*)&Asm[ldsoff + 4] = make_ushort4(f2bf(v1.x), f2bf(v1.y), f2bf(v1.z), f2bf(v1.w));
        *(uint4*)&Bsm[ldsoff] = *(const uint4*)(W2T + (size_t)(n0 + row) * CDIM + k0 + c8 * 8);
      }
      __syncthreads();
      COMPUTE();
      __syncthreads();
    }
  }

  // ---- epilogue: regs -> LDS [128ch][136] u16 -> coalesced 16B stores ----
  u16* et = smem;                               // 128 x 136 u16 = 34KB
  const int b = m0 >> 14;
  const int TOK0 = m0 & (NTOK - 1);
  const int region = n0 / CDIM;                 // uniform per block (384 = 3*128)
#pragma unroll
  for (int cb = 0; cb < 2; ++cb) {
    const int cl = wc * 32 + cb * 16 + lm;      // local channel 0..127
    const int c = (n0 - region * CDIM) + cl;    // 0..383
    float inv = 1.0f;
    if (region == 0 || region == 2) inv = 1.0f / log1pf(expf(ldx1(scale_p, c, f32)));
#pragma unroll
    for (int r = 0; r < 4; ++r) {
      const int tl = wr * 64 + r * 16 + lq * 4; // local token 0..127
      const f32x4 v = acc[r][cb];
      ushort4 w;
      if (region == 2) {
        const int tok = TOK0 + tl;
        const float p0 = ldx1(pos_enc, (size_t)(tok + 0) * CDIM + c, f32);
        const float p1 = ldx1(pos_enc, (size_t)(tok + 1) * CDIM + c, f32);
        const float p2 = ldx1(pos_enc, (size_t)(tok + 2) * CDIM + c, f32);
        const float p3 = ldx1(pos_enc, (size_t)(tok + 3) * CDIM + c, f32);
        w = make_ushort4(f2bf((v[0] + p0) * inv), f2bf((v[1] + p1) * inv),
                         f2bf((v[2] + p2) * inv), f2bf((v[3] + p3) * inv));
      } else if (region == 0) {
        w = make_ushort4(f2bf(v[0] * inv), f2bf(v[1] * inv), f2bf(v[2] * inv), f2bf(v[3] * inv));
      } else {
        w = make_ushort4(f2bf(v[0]), f2bf(v[1]), f2bf(v[2]), f2bf(v[3]));
      }
      *(ushort4*)&et[cl * 136 + tl] = w;
    }
  }
  __syncthreads();
  u16* dst = (region == 0) ? qsT : (region == 1) ? gT : (region == 2) ? ksT : vT;
  const int cbase = b * CDIM + (n0 - region * CDIM);
#pragma unroll
  for (int i = 0; i < 4; ++i) {
    const int idx = i * 512 + t;
    const int row = idx >> 4, seg = idx & 15;   // row = channel, seg = 16B chunk
    const uint4 val = *(const uint4*)&et[row * 136 + seg * 8];
    *(uint4*)(dst + ((size_t)(cbase + row)) * NTOK + TOK0 + seg * 8) = val;
  }
}

// ---------------- k2: per (b,h): km[96] = mean(kk), kvm[96][48] = kk^T v / N -------
// R14: pad 65->68, float4 fill writes, nn-unroll-4 float4 MAC reads (4x fewer
// LDS instructions; identical f32 math).
__global__ __launch_bounds__(256) void k2_stats(
    const u16* __restrict__ ksT, const u16* __restrict__ vT,
    const void* __restrict__ power_p, const int* __restrict__ flag,
    float* __restrict__ km, float* __restrict__ kvm)
{
  const bool f32 = (*flag != 0);
  __shared__ float kkL[96][68];
  __shared__ float vL[48][68];
  __shared__ float pw[48];
  const int bh = blockIdx.x;
  const int b = bh >> 3, h = bh & 7;
  const int t = threadIdx.x;
  if (t < 48) pw[t] = 1.0f + 4.0f / (1.0f + expf(-ldx1(power_p, h * HDIM + t, f32)));
  __syncthreads();
  const int td = t & 15, te = t >> 4;
  float acc[6][3] = {};
  float ksum = 0.0f;
  const u16* ksbase = ksT + ((size_t)(b * CDIM + h * HDIM)) * NTOK;
  const u16* vbase  = vT  + ((size_t)(b * CDIM + h * HDIM)) * NTOK;
  const int n0base = blockIdx.y * 1024;
  for (int tile = 0; tile < 16; ++tile) {
    const int n0 = n0base + tile * 64;
    for (int i = t; i < 48 * 16; i += 256) {
      const int c = i >> 4, qd = (i & 15) * 4;
      ushort4 kq = *(const ushort4*)(ksbase + (size_t)c * NTOK + n0 + qd);
      ushort4 vq = *(const ushort4*)(vbase  + (size_t)c * NTOK + n0 + qd);
      const float p = pw[c];
      float kf[4] = {bf2f(kq.x), bf2f(kq.y), bf2f(kq.z), bf2f(kq.w)};
      float4 pos, neg;
#pragma unroll
      for (int jj = 0; jj < 4; ++jj) {
        const float f = pow_mag(fabsf(kf[jj]), p);
        ((float*)&pos)[jj] = (kf[jj] > 0.f) ? f : 0.f;
        ((float*)&neg)[jj] = (kf[jj] < 0.f) ? f : 0.f;
      }
      *(float4*)&kkL[c][qd]      = pos;
      *(float4*)&kkL[c + 48][qd] = neg;
      *(float4*)&vL[c][qd] = make_float4(bf2f(vq.x), bf2f(vq.y), bf2f(vq.z), bf2f(vq.w));
    }
    __syncthreads();
#pragma unroll 2
    for (int nn = 0; nn < 64; nn += 4) {
      float4 av[6], bv[3];
#pragma unroll
      for (int i = 0; i < 6; ++i) av[i] = *(const float4*)&kkL[td * 6 + i][nn];
#pragma unroll
      for (int j = 0; j < 3; ++j) bv[j] = *(const float4*)&vL[te * 3 + j][nn];
#pragma unroll
      for (int i = 0; i < 6; ++i)
#pragma unroll
        for (int j = 0; j < 3; ++j) {
          acc[i][j] = fmaf(av[i].x, bv[j].x, acc[i][j]);
          acc[i][j] = fmaf(av[i].y, bv[j].y, acc[i][j]);
          acc[i][j] = fmaf(av[i].z, bv[j].z, acc[i][j]);
          acc[i][j] = fmaf(av[i].w, bv[j].w, acc[i][j]);
        }
    }
    if (t < 96) {
#pragma unroll
      for (int nn = 0; nn < 64; nn += 4) {
        const float4 kq4 = *(const float4*)&kkL[t][nn];
        ksum += (kq4.x + kq4.y) + (kq4.z + kq4.w);
      }
    }
    __syncthreads();
  }
  const float inv_n = 1.0f / (float)NTOK;
#pragma unroll
  for (int i = 0; i < 6; ++i)
#pragma unroll
    for (int j = 0; j < 3; ++j)
      atomicAdd(&kvm[(size_t)bh * 96 * 48 + (td * 6 + i) * 48 + (te * 3 + j)], acc[i][j] * inv_n);
  if (t < 96) atomicAdd(&km[bh * 96 + t], ksum * inv_n);
}

// ---------------- k3: q features, z-norm, x_sim/x_opp; attn -> ksT -----------------
__global__ __launch_bounds__(256) void k3_attn(
    const u16* __restrict__ qsT, u16* __restrict__ attnT,
    const float* __restrict__ km_g, const float* __restrict__ kvm_g,
    const void* __restrict__ power_p, const int* __restrict__ flag)
{
  const bool f32 = (*flag != 0);
  __shared__ __align__(16) float kvmL[96][48];
  __shared__ float kmL[96];
  __shared__ float pw[48];
  const int bh = blockIdx.y;
  const int b = bh >> 3, h = bh & 7;
  const int t = threadIdx.x;
  for (int i = t; i < 96 * 48; i += 256) kvmL[i / 48][i % 48] = kvm_g[(size_t)bh * 96 * 48 + i];
  if (t < 96) kmL[t] = km_g[bh * 96 + t];
  if (t < 48) pw[t] = 1.0f + 4.0f / (1.0f + expf(-ldx1(power_p, h * HDIM + t, f32)));
  __syncthreads();
  const int n = blockIdx.x * 512 + t;
  const size_t chan0 = ((size_t)(b * CDIM + h * HDIM)) * NTOK + n;
  const u16* qbase = qsT + chan0;
  u16* obase = attnT + chan0;
  float4 accs[2][6] = {}, acco[2][6] = {};
  float zs[2] = {}, zo[2] = {};
  for (int d = 0; d < 48; ++d) {
    const float p = pw[d];
    float qp[2], qn[2];
#pragma unroll
    for (int i = 0; i < 2; ++i) {
      const float qv = bf2f(qbase[(size_t)d * NTOK + i * 256]);
      const float f = pow_mag(fabsf(qv), p);
      qp[i] = (qv > 0.f) ? f : 0.f;
      qn[i] = (qv < 0.f) ? f : 0.f;
      zs[i] = fmaf(qp[i], kmL[d], zs[i]); zs[i] = fmaf(qn[i], kmL[d + 48], zs[i]);
      zo[i] = fmaf(qn[i], kmL[d], zo[i]); zo[i] = fmaf(qp[i], kmL[d + 48], zo[i]);
    }
#pragma unroll
    for (int e4 = 0; e4 < 6; ++e4) {
      const float4 kvA = *(const float4*)&kvmL[d][e4 * 4];
      const float4 kvB = *(const float4*)&kvmL[d + 48][e4 * 4];
      const float4 kvC = *(const float4*)&kvmL[d][24 + e4 * 4];
      const float4 kvD = *(const float4*)&kvmL[d + 48][24 + e4 * 4];
#pragma unroll
      for (int i = 0; i < 2; ++i) {
        accs[i][e4].x = fmaf(qp[i], kvA.x, fmaf(qn[i], kvB.x, accs[i][e4].x));
        accs[i][e4].y = fmaf(qp[i], kvA.y, fmaf(qn[i], kvB.y, accs[i][e4].y));
        accs[i][e4].z = fmaf(qp[i], kvA.z, fmaf(qn[i], kvB.z, accs[i][e4].z));
        accs[i][e4].w = fmaf(qp[i], kvA.w, fmaf(qn[i], kvB.w, accs[i][e4].w));
        acco[i][e4].x = fmaf(qn[i], kvC.x, fmaf(qp[i], kvD.x, acco[i][e4].x));
        acco[i][e4].y = fmaf(qn[i], kvC.y, fmaf(qp[i], kvD.y, acco[i][e4].y));
        acco[i][e4].z = fmaf(qn[i], kvC.z, fmaf(qp[i], kvD.z, acco[i][e4].z));
        acco[i][e4].w = fmaf(qn[i], kvC.w, fmaf(qp[i], kvD.w, acco[i][e4].w));
      }
    }
  }
#pragma unroll
  for (int i = 0; i < 2; ++i) {
    const float zsi = 1.0f / (zs[i] + 1e-6f);
    const float zoi = 1.0f / (zo[i] + 1e-6f);
#pragma unroll
    for (int e4 = 0; e4 < 6; ++e4) {
      const float4 s = accs[i][e4], o = acco[i][e4];
      obase[(size_t)(e4 * 4 + 0) * NTOK + i * 256]    = f2bf(s.x * zsi);
      obase[(size_t)(e4 * 4 + 1) * NTOK + i * 256]    = f2bf(s.y * zsi);
      obase[(size_t)(e4 * 4 + 2) * NTOK + i * 256]    = f2bf(s.z * zsi);
      obase[(size_t)(e4 * 4 + 3) * NTOK + i * 256]    = f2bf(s.w * zsi);
      obase[(size_t)(24 + e4 * 4 + 0) * NTOK + i * 256] = f2bf(o.x * zoi);
      obase[(size_t)(24 + e4 * 4 + 1) * NTOK + i * 256] = f2bf(o.y * zoi);
      obase[(size_t)(24 + e4 * 4 + 2) * NTOK + i * 256] = f2bf(o.z * zoi);
      obase[(size_t)(24 + e4 * 4 + 3) * NTOK + i * 256] = f2bf(o.w * zoi);
    }
  }
}

// ---------------- k4: 5x5 depthwise conv on vT + out2 = (attn + conv) * g ----------
// R14: halo baked into tile [20][136] (col = gx+4, zero-padded); 4 outputs per
// thread via 3 aligned float4 reads + register-shifted stencil; ushort4 RMW.
__global__ __launch_bounds__(256) void k4_conv_combine(
    const u16* __restrict__ vT, const u16* __restrict__ gT,
    const void* __restrict__ dwc_w, const void* __restrict__ dwc_b,
    const int* __restrict__ flag,
    u16* __restrict__ attnT)
{
  const bool f32 = (*flag != 0);
  __shared__ float tile[20][136];
  const int bc = blockIdx.y;
  const int y0 = blockIdx.x * 16;
  const int t = threadIdx.x;
  const int d = bc % 48;
  float w[25];
#pragma unroll
  for (int i = 0; i < 25; ++i) w[i] = ldx1(dwc_w, d * 25 + i, f32);
  const float bias = ldx1(dwc_b, d, f32);
  const u16* vimg = vT + (size_t)bc * NTOK;
  for (int i = t; i < 20 * 34; i += 256) {
    const int r = i / 34, cq = (i - r * 34) * 4;   // tile col group (gx = col-4)
    const int gy = y0 + r - 2;
    float4 v4 = make_float4(0.f, 0.f, 0.f, 0.f);
    if (gy >= 0 && gy < IMGH) {
      const int gx0 = cq - 4;
      if (gx0 >= 0 && gx0 + 3 < IMGW) {
        const ushort4 u = *(const ushort4*)(vimg + gy * IMGW + gx0);
        v4 = make_float4(bf2f(u.x), bf2f(u.y), bf2f(u.z), bf2f(u.w));
      } else {
#pragma unroll
        for (int jj = 0; jj < 4; ++jj) {
          const int gx = gx0 + jj;
          ((float*)&v4)[jj] = (gx >= 0 && gx < IMGW) ? bf2f(vimg[gy * IMGW + gx]) : 0.f;
        }
      }
    }
    *(float4*)&tile[r][cq] = v4;
  }
  __syncthreads();
  u16* abase = attnT + (size_t)bc * NTOK;
  const u16* gbase = gT + (size_t)bc * NTOK;
#pragma unroll
  for (int pass = 0; pass < 2; ++pass) {
    const int yy = pass * 8 + (t >> 5);         // 0..15
    const int x0 = (t & 31) * 4;                // 0..124
    float a0 = bias, a1 = bias, a2 = bias, a3 = bias;
#pragma unroll
    for (int dy = 0; dy < 5; ++dy) {
      const float* row = &tile[yy + dy][0];
      const float4 A = *(const float4*)&row[x0];       // gx x0-4..x0-1
      const float4 B = *(const float4*)&row[x0 + 4];   // gx x0..x0+3
      const float4 C = *(const float4*)&row[x0 + 8];   // gx x0+4..x0+7
      const float c0 = A.z, c1 = A.w, c2 = B.x, c3 = B.y,
                  c4 = B.z, c5 = B.w, c6 = C.x, c7 = C.y;
      const float w0 = w[dy * 5 + 0], w1 = w[dy * 5 + 1], w2 = w[dy * 5 + 2],
                  w3 = w[dy * 5 + 3], w4 = w[dy * 5 + 4];
      a0 = fmaf(w0, c0, fmaf(w1, c1, fmaf(w2, c2, fmaf(w3, c3, fmaf(w4, c4, a0)))));
      a1 = fmaf(w0, c1, fmaf(w1, c2, fmaf(w2, c3, fmaf(w3, c4, fmaf(w4, c5, a1)))));
      a2 = fmaf(w0, c2, fmaf(w1, c3, fmaf(w2, c4, fmaf(w3, c5, fmaf(w4, c6, a2)))));
      a3 = fmaf(w0, c3, fmaf(w1, c4, fmaf(w2, c5, fmaf(w3, c6, fmaf(w4, c7, a3)))));
    }
    const int gidx = (y0 + yy) * IMGW + x0;
    const ushort4 at = *(const ushort4*)(abase + gidx);
    const ushort4 gg = *(const ushort4*)(gbase + gidx);
    *(ushort4*)(abase + gidx) = make_ushort4(
        f2bf((bf2f(at.x) + a0) * bf2f(gg.x)),
        f2bf((bf2f(at.y) + a1) * bf2f(gg.y)),
        f2bf((bf2f(at.z) + a2) * bf2f(gg.z)),
        f2bf((bf2f(at.w) + a3) * bf2f(gg.w)));
  }
}

// ---------------- k4b: transpose out2 channel-major -> token-major -----------------
__global__ __launch_bounds__(256) void k4b_transpose(
    const u16* __restrict__ src,   // [(b*384+c)][n]
    u16* __restrict__ dst)         // [(b*16384+n)][c]
{
  __shared__ u16 tile[64][68];
  const int b  = blockIdx.z;
  const int c0 = blockIdx.y * 64;
  const int n0 = blockIdx.x * 64;
  const int t = threadIdx.x;
  const int tr = t >> 4, tq = t & 15;
#pragma unroll
  for (int i = 0; i < 4; ++i) {
    const int r = tr + i * 16;     // c-row
    *(ushort4*)&tile[r][tq * 4] =
        *(const ushort4*)(src + ((size_t)(b * CDIM + c0 + r)) * NTOK + n0 + tq * 4);
  }
  __syncthreads();
#pragma unroll
  for (int i = 0; i < 4; ++i) {
    const int n = tr + i * 16;     // token-row
    const ushort4 vv = make_ushort4(tile[tq * 4 + 0][n], tile[tq * 4 + 1][n],
                                    tile[tq * 4 + 2][n], tile[tq * 4 + 3][n]);
    *(ushort4*)(dst + ((size_t)(b * NTOK + n0 + n)) * CDIM + c0 + tq * 4) = vv;
  }
}

// ---------------- k5: MFMA GEMM out2_tm @ Wproj + b -> d_out -----------------------
// T3 2-phase dbuf K-loop (R9); coalesced fp32 epilogue via LDS (2 passes).
__global__ __launch_bounds__(256) void k5_mfma(
    const u16* __restrict__ A,     // [row=b*16384+n][c] bf16
    const u16* __restrict__ WpT,   // [c_out][c_in] bf16
    const void* __restrict__ bp, const int* __restrict__ flag,
    void* __restrict__ out)
{
  const bool f32 = (*flag != 0);
  // flat 64KB: A dbuf [0..16384), B dbuf [16384..32768) u16.
  // epilogue overlays first 33.8KB as float ef[64][132].
  __shared__ __align__(16) u16 smem[32768];
  u16* Asm0 = smem;
  u16* Asm1 = smem + 8192;
  u16* Bsm0 = smem + 16384;
  u16* Bsm1 = smem + 24576;
  const int t = threadIdx.x;
  const int bid = blockIdx.x;                   // 0..1535
  const int rm = (bid & 7) * 192 + (bid >> 3);  // XCD-contiguous remap
  const int m_idx = rm / 3;
  const int n_idx = rm - m_idx * 3;
  const int n0 = n_idx * 128;                   // 0..383
  const int m0 = m_idx * 128;
  const int wave = t >> 6, lane = t & 63;
  const int wr = wave >> 1, wc = wave & 1;
  const int lm = lane & 15, lq = lane >> 4;

  f32x4 acc[4][4] = {};

  auto STAGE = [&](int buf, int k0) {
    u16* Ab = buf ? Asm1 : Asm0;
    u16* Bb = buf ? Bsm1 : Bsm0;
#pragma unroll
    for (int i = 0; i < 4; ++i) {
      const int chunk = i * 256 + t;
      const int row = chunk >> 3, c8 = chunk & 7;
      const int sc8 = c8 ^ (row & 7);           // source-side swizzle
      u16* lpA = &Ab[(i * 256 + wave * 64) * 8];
      u16* lpB = &Bb[(i * 256 + wave * 64) * 8];
      gload16(lpA, A + (size_t)(m0 + row) * CDIM + k0 + sc8 * 8);
      gload16(lpB, WpT + (size_t)(n0 + row) * CDIM + k0 + sc8 * 8);
    }
  };
  auto COMPUTE = [&](int buf) {
    u16* Ab = buf ? Asm1 : Asm0;
    u16* Bb = buf ? Bsm1 : Bsm0;
#pragma unroll
    for (int kh = 0; kh < 2; ++kh) {
      bf16x8 af[4], bfr[4];
#pragma unroll
      for (int r = 0; r < 4; ++r) {
        const int row = wr * 64 + r * 16 + lm;
        af[r] = *(const bf16x8*)&Ab[row * 64 + (((kh * 4 + lq) ^ (row & 7)) * 8)];
      }
#pragma unroll
      for (int cb = 0; cb < 4; ++cb) {
        const int row = wc * 64 + cb * 16 + lm;
        bfr[cb] = *(const bf16x8*)&Bb[row * 64 + (((kh * 4 + lq) ^ (row & 7)) * 8)];
      }
#pragma unroll
      for (int r = 0; r < 4; ++r)
#pragma unroll
        for (int cb = 0; cb < 4; ++cb)
          acc[r][cb] = __builtin_amdgcn_mfma_f32_16x16x32_bf16(af[r], bfr[cb], acc[r][cb], 0, 0, 0);
    }
  };

  STAGE(0, 0);
  asm volatile("s_waitcnt vmcnt(0)" ::: "memory");
  __builtin_amdgcn_sched_barrier(0);
  __builtin_amdgcn_s_barrier();
  int cur = 0;
#pragma unroll
  for (int ks = 0; ks < 5; ++ks) {
    STAGE(cur ^ 1, (ks + 1) * 64);
    COMPUTE(cur);
    asm volatile("s_waitcnt vmcnt(0)" ::: "memory");
    __builtin_amdgcn_sched_barrier(0);
    __builtin_amdgcn_s_barrier();
    cur ^= 1;
  }
  COMPUTE(cur);

  if (f32) {
    // ---- coalesced fp32 epilogue: 2 half-tile passes through LDS ----
    float* ef = (float*)smem;                   // 64 x 132 f32 = 33.8KB
    float bb[4];
#pragma unroll
    for (int cb = 0; cb < 4; ++cb) bb[cb] = ((const float*)bp)[n0 + wc * 64 + cb * 16 + lm];
    for (int h = 0; h < 2; ++h) {
      __syncthreads();                          // K-loop reads / prev pass done
      if (wr == h) {
#pragma unroll
        for (int cb = 0; cb < 4; ++cb) {
          const int cl = wc * 64 + cb * 16 + lm;    // 0..127
#pragma unroll
          for (int r = 0; r < 4; ++r) {
            const int tl = r * 16 + lq * 4;         // 0..63 in half-tile
            const f32x4 v = acc[r][cb];
#pragma unroll
            for (int reg = 0; reg < 4; ++reg)
              ef[(tl + reg) * 132 + cl] = v[reg] + bb[cb];
          }
        }
      }
      __syncthreads();
      // store 64 rows x 128 c: 512B contiguous per row
      float* ob = (float*)out + (size_t)(m0 + h * 64) * CDIM + n0;
#pragma unroll
      for (int i = 0; i < 8; ++i) {
        const int idx = i * 256 + t;
        const int row = idx >> 5, seg = idx & 31; // 32 x float4 per row
        const float4 val = *(const float4*)&ef[row * 132 + seg * 4];
        *(float4*)(ob + (size_t)row * CDIM + seg * 4) = val;
      }
    }
  } else {
    // bf16 out: original scattered path (rare)
#pragma unroll
    for (int cb = 0; cb < 4; ++cb) {
      const int cg = n0 + wc * 64 + cb * 16 + lm;
      const float bbs = bf2f(((const u16*)bp)[cg]);
#pragma unroll
      for (int r = 0; r < 4; ++r) {
        const int rowtok = m0 + wr * 64 + r * 16 + lq * 4;
        const f32x4 v = acc[r][cb];
#pragma unroll
        for (int reg = 0; reg < 4; ++reg) {
          const size_t o = (size_t)(rowtok + reg) * CDIM + cg;
          ((u16*)out)[o] = f2bf(v[reg] + bbs);
        }
      }
    }
  }
}

extern "C" void kernel_launch(void* const* d_in, const int* in_sizes, int n_in,
                              void* d_out, int out_size, void* d_ws, size_t ws_size,
                              hipStream_t stream) {
  const void* x       = d_in[0];
  const void* Wqg     = d_in[1];
  const void* Wkv     = d_in[2];
  const void* Wproj   = d_in[3];
  const void* bproj   = d_in[4];
  const void* pos_enc = d_in[5];
  const void* power_p = d_in[6];
  const void* scale_p = d_in[7];
  const void* dwc_w   = d_in[8];
  const void* dwc_b   = d_in[9];

  const size_t S = (size_t)NB * NTOK * CDIM;                 // 25,165,824
  const size_t stats_off   = 256;
  const size_t stats_bytes = (size_t)(32 * 96 + 32 * 96 * 48) * sizeof(float);
  const size_t w2t_elems = 1536 * 384, wpt_elems = 384 * 384;
  const size_t need = stats_off + stats_bytes + 3 * S * sizeof(u16)
                    + (w2t_elems + wpt_elems) * sizeof(u16);
  if (ws_size < need) return;

  int*   flag = (int*)d_ws;
  float* km   = (float*)((char*)d_ws + stats_off);
  float* kvm  = km + 32 * 96;
  u16* qsT = (u16*)((char*)d_ws + stats_off + stats_bytes);  // q/scale; later out2_tm
  u16* gT  = qsT + S;
  u16* ksT = gT + S;                                         // k feats; attn; out2
  u16* W2T = ksT + S;
  u16* WpT = W2T + w2t_elems;
  u16* vT  = (u16*)d_out;                                    // dead before k5 writes

  // bf16 scratch for x lives in the SECOND half of d_out when out is fp32
  // (bytes [2S, 4S) -- disjoint from vT's [0, 2S); dead once k1 completes,
  // k5 overwrites the whole out buffer afterwards).
  const int conv_ok = (out_size >= (int)(S * 4)) ? 1 : 0;
  u16* xbf = conv_ok ? ((u16*)d_out + S) : (u16*)d_out;      // unused if !conv_ok

  hipMemsetAsync(km, 0, stats_bytes, stream);

  k0_detect<<<1, 256, 0, stream>>>(x, flag);
  if (conv_ok) kx_convert<<<2048, 256, 0, stream>>>(x, flag, xbf);
  kprep<<<(int)((w2t_elems + wpt_elems + 255) / 256), 256, 0, stream>>>(
      Wqg, Wkv, Wproj, flag, W2T, WpT);
  k1_mfma<<<6144, 512, 0, stream>>>(x, xbf, W2T, pos_enc, scale_p, flag, conv_ok,
                                    qsT, gT, ksT, vT);
  k2_stats<<<dim3(32, 16), 256, 0, stream>>>(ksT, vT, power_p, flag, km, kvm);
  k3_attn<<<dim3(32, 32), 256, 0, stream>>>(qsT, ksT, km, kvm, power_p, flag);
  k4_conv_combine<<<dim3(8, 1536), 256, 0, stream>>>(vT, gT, dwc_w, dwc_b, flag, ksT);
  k4b_transpose<<<dim3(256, 6, 4), 256, 0, stream>>>(ksT, qsT);
  k5_mfma<<<1536, 256, 0, stream>>>(qsT, WpT, bproj, flag, d_out);
}

// Round 15
// 667.680 us; speedup vs baseline: 1.1924x; 1.1334x over previous
//
#include <hip/hip_runtime.h>
#include <math.h>

// PolaLinearAttention, MI355X round 15: k2 -> MFMA.
// R14 post-mortem: k2/k4 float4 vectorization bought 40us (796->757, k1
// control exact at 204); k2's remaining floor is LDS DATA volume: f32 MAC
// moves 576 f32/thread/tile = 4.7M b128 total ~ 92us at 12cy/b128, occupancy-
// independent. Fix: kvm[96][48] = kk.v^T is k1's exact MFMA pattern. Features
// in LDS as bf16 ([96][72],[48][72]); waves 0-2 own 32-row M-slabs x 3 N-tiles
// -> 12 mfma_f32_16x16x32_bf16 + 10 ds_read_b128 per K=64 tile (14x less LDS).
// v is already bf16 (straight copy); kk gets one extra bf16 rounding (same
// class as existing qsT/ksT/vT quantization); fp32 MFMA accumulate; ksum from
// the same bf16 rows. Only k2 changed; k1 (204us) = control.
// Layout: intermediates channel-major T: (b*384+c)*16384 + n (bf16).
//   qsT,gT,ksT in ws; vT in d_out (dead before k5 writes); xbf in d_out[2S,4S).
// ws: flag|stats(0.6MB)|qsT,gT,ksT(151MB)|W2T,WpT(1.5MB) ~= 154MB (guarded).

#define NB 4
#define NTOK 16384
#define CDIM 384
#define NHEAD 8
#define HDIM 48
#define IMGH 128
#define IMGW 128

typedef unsigned short u16;
typedef unsigned int u32;
typedef __attribute__((ext_vector_type(8))) short bf16x8;
typedef __attribute__((ext_vector_type(4))) float f32x4;

__device__ __forceinline__ float bf2f(u16 u) {
  return __uint_as_float(((unsigned)u) << 16);
}
__device__ __forceinline__ u16 f2bf(float f) {
  unsigned u = __float_as_uint(f);
  u += 0x7FFF + ((u >> 16) & 1);   // RNE
  return (u16)(u >> 16);
}
// |v|^p, safe: never logs non-positive, never inf/NaN.
__device__ __forceinline__ float pow_mag(float r, float p) {
  if (r < 1e-20f) return 0.0f;
  return exp2f(fminf(p * log2f(r), 80.0f));
}
// dual-dtype loads for EXTERNAL tensors
__device__ __forceinline__ float ldx1(const void* p, size_t i, bool f32) {
  return f32 ? ((const float*)p)[i] : bf2f(((const u16*)p)[i]);
}
// async global->LDS 16B: LDS dest is wave-uniform base + lane*16.
__device__ __forceinline__ void gload16(u16* lds, const u16* g) {
  __builtin_amdgcn_global_load_lds(
      (const __attribute__((address_space(1))) u32*)g,
      (__attribute__((address_space(3))) u32*)lds, 16, 0, 0);
}

// ---------------- k0: dtype detector ------------------------------------------------
__global__ __launch_bounds__(256) void k0_detect(const void* __restrict__ x,
                                                 int* __restrict__ flag) {
  __shared__ int s[256];
  const u16* p = (const u16*)x;
  const int t = threadIdx.x;
  int good = 0;
#pragma unroll
  for (int i = 0; i < 16; ++i) {
    const u16 w = p[t * 16 + i];
    const int e = (w >> 7) & 0xFF;
    good += (e >= 0x60 && e <= 0x85) ? 1 : 0;   // sane bf16 exponent
  }
  s[t] = good;
  __syncthreads();
  for (int o = 128; o > 0; o >>= 1) {
    if (t < o) s[t] += s[t + o];
    __syncthreads();
  }
  if (t == 0) *flag = (s[0] >= (4096 * 4) / 5) ? 0 : 1;  // 0 = bf16, 1 = fp32
}

// ---------------- kx: one-shot x fp32 -> bf16 (only when out buffer is fp32) -------
__global__ __launch_bounds__(256) void kx_convert(const void* __restrict__ x,
                                                  const int* __restrict__ flag,
                                                  u16* __restrict__ xbf) {
  if (*flag == 0) return;                       // input already bf16
  const size_t S = (size_t)NB * NTOK * CDIM;
  const size_t tid = (size_t)blockIdx.x * 256 + threadIdx.x;
  const size_t stride = (size_t)gridDim.x * 256;
  const float4* xf = (const float4*)x;
  for (size_t i = tid; i < S / 8; i += stride) {
    const float4 a = xf[i * 2 + 0];
    const float4 b = xf[i * 2 + 1];
    *(ushort4*)(xbf + i * 8 + 0) = make_ushort4(f2bf(a.x), f2bf(a.y), f2bf(a.z), f2bf(a.w));
    *(ushort4*)(xbf + i * 8 + 4) = make_ushort4(f2bf(b.x), f2bf(b.y), f2bf(b.z), f2bf(b.w));
  }
}

// ---------------- kprep: bf16 transposed weights -----------------------------------
__global__ __launch_bounds__(256) void kprep(
    const void* __restrict__ Wqg, const void* __restrict__ Wkv,
    const void* __restrict__ Wp, const int* __restrict__ flag,
    u16* __restrict__ W2T, u16* __restrict__ WpT)
{
  const bool f32 = (*flag != 0);
  const int idx = blockIdx.x * 256 + threadIdx.x;
  if (idx < 1536 * 384) {
    const int n = idx / 384, k = idx - n * 384;
    const float v = (n < 768) ? ldx1(Wqg, (size_t)k * 768 + n, f32)
                              : ldx1(Wkv, (size_t)k * 768 + (n - 768), f32);
    W2T[idx] = f2bf(v);
  } else {
    const int j = idx - 1536 * 384;
    if (j < 384 * 384) {
      const int n = j / 384, k = j - n * 384;
      WpT[j] = f2bf(ldx1(Wp, (size_t)k * 384 + n, f32));
    }
  }
}

// ---------------- k1: MFMA GEMM x @ [Wqg|Wkv] -> qsT,gT,ksT,vT ---------------------
// 128(M tok) x 128(N ch) tile, BK=64, 8 waves (2M x 4N, each 64tok x 32ch).
// Single-buffered staging (34KB block LDS -> 4 blocks/CU); coalesced epilogue.
__global__ __launch_bounds__(512) void k1_mfma(
    const void* __restrict__ x, const u16* __restrict__ xbf,
    const u16* __restrict__ W2T,
    const void* __restrict__ pos_enc, const void* __restrict__ scale_p,
    const int* __restrict__ flag, const int conv_ok,
    u16* __restrict__ qsT, u16* __restrict__ gT, u16* __restrict__ ksT, u16* __restrict__ vT)
{
  const bool f32 = (*flag != 0);
  const bool fast = (!f32) || (conv_ok != 0);   // bf16 source available
  const u16* Asrc = f32 ? xbf : (const u16*)x;
  // 34KB union: staging A[0..8191] + B[8192..16383]; epilogue et[0..17407].
  __shared__ __align__(16) u16 smem[17408];
  u16* Asm = smem;                              // [128][64] u16, XOR-swz contents
  u16* Bsm = smem + 8192;                       // [128][64]
  const int t = threadIdx.x;
  const int bid = blockIdx.x;                   // 0..6143
  const int rm = (bid & 7) * 768 + (bid >> 3);  // XCD-contiguous remap
  const int m_idx = rm / 12;
  const int n_idx = rm - m_idx * 12;
  const int n0 = n_idx * 128;                   // 0..1535
  const int m0 = m_idx * 128;                   // 0..65535
  const int wave = t >> 6, lane = t & 63;
  const int wr = wave >> 2, wc = wave & 3;      // 2M x 4N
  const int lm = lane & 15, lq = lane >> 4;

  f32x4 acc[4][2] = {};

  // stage one 128x64 A-tile + B-tile (2+2 gload16/thread)
  auto STAGE = [&](int k0) {
#pragma unroll
    for (int i = 0; i < 2; ++i) {
      const int chunk = i * 512 + t;            // 0..1023 chunks of 8 u16
      const int row = chunk >> 3, c8 = chunk & 7;
      const int sc8 = c8 ^ (row & 7);           // source-side swizzle
      u16* lpA = &Asm[(i * 512 + wave * 64) * 8];   // wave-uniform base
      u16* lpB = &Bsm[(i * 512 + wave * 64) * 8];
      gload16(lpA, Asrc + (size_t)(m0 + row) * CDIM + k0 + sc8 * 8);
      gload16(lpB, W2T + (size_t)(n0 + row) * CDIM + k0 + sc8 * 8);
    }
  };
  auto COMPUTE = [&]() {
#pragma unroll
    for (int kh = 0; kh < 2; ++kh) {
      bf16x8 af[4], bfr[2];
#pragma unroll
      for (int r = 0; r < 4; ++r) {
        const int row = wr * 64 + r * 16 + lm;
        af[r] = *(const bf16x8*)&Asm[row * 64 + (((kh * 4 + lq) ^ (row & 7)) * 8)];
      }
#pragma unroll
      for (int cb = 0; cb < 2; ++cb) {
        const int row = wc * 32 + cb * 16 + lm;
        bfr[cb] = *(const bf16x8*)&Bsm[row * 64 + (((kh * 4 + lq) ^ (row & 7)) * 8)];
      }
#pragma unroll
      for (int r = 0; r < 4; ++r)
#pragma unroll
        for (int cb = 0; cb < 2; ++cb)
          acc[r][cb] = __builtin_amdgcn_mfma_f32_16x16x32_bf16(af[r], bfr[cb], acc[r][cb], 0, 0, 0);
    }
  };

  if (fast) {
    for (int ks = 0; ks < 6; ++ks) {
      STAGE(ks * 64);
      __syncthreads();                          // drains vmcnt -> tile landed
      COMPUTE();
      __syncthreads();                          // reads done before next STAGE
    }
  } else {
    // fallback: fp32 input but no bf16 scratch (out buffer too small)
    for (int k0 = 0; k0 < CDIM; k0 += 64) {
#pragma unroll
      for (int i = 0; i < 2; ++i) {
        const int chunk = t + i * 512;
        const int row = chunk >> 3, c8 = chunk & 7;
        const int ldsoff = row * 64 + ((c8 ^ (row & 7)) * 8);
        const float* xp = (const float*)x + (size_t)(m0 + row) * CDIM + k0 + c8 * 8;
        const float4 v0 = *(const float4*)xp;
        const float4 v1 = *(const float4*)(xp + 4);
        *(ushort4*)&Asm[ldsoff]     = make_ushort4(f2bf(v0.x), f2bf(v0.y), f2bf(v0.z), f2bf(v0.w));
        *(ushort4*)&Asm[ldsoff + 4] = make_ushort4(f2bf(v1.x), f2bf(v1.y), f2bf(v1.z), f2bf(v1.w));
        *(uint4*)&Bsm[ldsoff] = *(const uint4*)(W2T + (size_t)(n0 + row) * CDIM + k0 + c8 * 8);
      }
      __syncthreads();
      COMPUTE();
      __syncthreads();
    }
  }

  // ---- epilogue: regs -> LDS [128ch][136] u16 -> coalesced 16B stores ----
  u16* et = smem;                               // 128 x 136 u16 = 34KB
  const int b = m0 >> 14;
  const int TOK0 = m0 & (NTOK - 1);
  const int region = n0 / CDIM;                 // uniform per block (384 = 3*128)
#pragma unroll
  for (int cb = 0; cb < 2; ++cb) {
    const int cl = wc * 32 + cb * 16 + lm;      // local channel 0..127
    const int c = (n0 - region * CDIM) + cl;    // 0..383
    float inv = 1.0f;
    if (region == 0 || region == 2) inv = 1.0f / log1pf(expf(ldx1(scale_p, c, f32)));
#pragma unroll
    for (int r = 0; r < 4; ++r) {
      const int tl = wr * 64 + r * 16 + lq * 4; // local token 0..127
      const f32x4 v = acc[r][cb];
      ushort4 w;
      if (region == 2) {
        const int tok = TOK0 + tl;
        const float p0 = ldx1(pos_enc, (size_t)(tok + 0) * CDIM + c, f32);
        const float p1 = ldx1(pos_enc, (size_t)(tok + 1) * CDIM + c, f32);
        const float p2 = ldx1(pos_enc, (size_t)(tok + 2) * CDIM + c, f32);
        const float p3 = ldx1(pos_enc, (size_t)(tok + 3) * CDIM + c, f32);
        w = make_ushort4(f2bf((v[0] + p0) * inv), f2bf((v[1] + p1) * inv),
                         f2bf((v[2] + p2) * inv), f2bf((v[3] + p3) * inv));
      } else if (region == 0) {
        w = make_ushort4(f2bf(v[0] * inv), f2bf(v[1] * inv), f2bf(v[2] * inv), f2bf(v[3] * inv));
      } else {
        w = make_ushort4(f2bf(v[0]), f2bf(v[1]), f2bf(v[2]), f2bf(v[3]));
      }
      *(ushort4*)&et[cl * 136 + tl] = w;
    }
  }
  __syncthreads();
  u16* dst = (region == 0) ? qsT : (region == 1) ? gT : (region == 2) ? ksT : vT;
  const int cbase = b * CDIM + (n0 - region * CDIM);
#pragma unroll
  for (int i = 0; i < 4; ++i) {
    const int idx = i * 512 + t;
    const int row = idx >> 4, seg = idx & 15;   // row = channel, seg = 16B chunk
    const uint4 val = *(const uint4*)&et[row * 136 + seg * 8];
    *(uint4*)(dst + ((size_t)(cbase + row)) * NTOK + TOK0 + seg * 8) = val;
  }
}

// ---------------- k2: per (b,h): km[96] = mean(kk), kvm[96][48] = kk^T v / N -------
// R15: MFMA. Features bf16 in LDS ([96][72],[48][72]); waves 0-2 own 32-row
// M-slabs x 3 N-tiles: 12 mfma_16x16x32_bf16 + 10 b128 per K=64 tile (vs 144
// b128 + 1152 VALU FMA). fp32 accumulate; ksum from same bf16 rows.
__global__ __launch_bounds__(256) void k2_stats(
    const u16* __restrict__ ksT, const u16* __restrict__ vT,
    const void* __restrict__ power_p, const int* __restrict__ flag,
    float* __restrict__ km, float* __restrict__ kvm)
{
  const bool f32 = (*flag != 0);
  __shared__ __align__(16) u16 kkL[96][72];   // bf16 features (stride 144B, 16B-aligned)
  __shared__ __align__(16) u16 vL[48][72];    // bf16 v
  __shared__ float pw[48];
  const int bh = blockIdx.x;
  const int b = bh >> 3, h = bh & 7;
  const int t = threadIdx.x;
  if (t < 48) pw[t] = 1.0f + 4.0f / (1.0f + expf(-ldx1(power_p, h * HDIM + t, f32)));
  __syncthreads();
  const int wave = t >> 6, lane = t & 63;
  const int lm = lane & 15, lq = lane >> 4;
  f32x4 acc[2][3] = {};                       // waves 0..2: [M-tile][N-tile]
  float ksum = 0.0f;
  const u16* ksbase = ksT + ((size_t)(b * CDIM + h * HDIM)) * NTOK;
  const u16* vbase  = vT  + ((size_t)(b * CDIM + h * HDIM)) * NTOK;
  const int n0base = blockIdx.y * 1024;
  for (int tile = 0; tile < 16; ++tile) {
    const int n0 = n0base + tile * 64;
    for (int i = t; i < 48 * 16; i += 256) {
      const int c = i >> 4, qd = (i & 15) * 4;
      ushort4 kq = *(const ushort4*)(ksbase + (size_t)c * NTOK + n0 + qd);
      ushort4 vq = *(const ushort4*)(vbase  + (size_t)c * NTOK + n0 + qd);
      const float p = pw[c];
      float kf[4] = {bf2f(kq.x), bf2f(kq.y), bf2f(kq.z), bf2f(kq.w)};
      ushort4 pos, neg;
#pragma unroll
      for (int jj = 0; jj < 4; ++jj) {
        const float f = pow_mag(fabsf(kf[jj]), p);
        ((u16*)&pos)[jj] = f2bf((kf[jj] > 0.f) ? f : 0.f);
        ((u16*)&neg)[jj] = f2bf((kf[jj] < 0.f) ? f : 0.f);
      }
      *(ushort4*)&kkL[c][qd]      = pos;
      *(ushort4*)&kkL[c + 48][qd] = neg;
      *(ushort4*)&vL[c][qd]       = vq;       // already bf16
    }
    __syncthreads();
    if (wave < 3) {
      const int mbase = wave * 32;
#pragma unroll
      for (int kh = 0; kh < 2; ++kh) {
        bf16x8 af[2], bfr[3];
#pragma unroll
        for (int mi = 0; mi < 2; ++mi)
          af[mi] = *(const bf16x8*)&kkL[mbase + mi * 16 + lm][kh * 32 + lq * 8];
#pragma unroll
        for (int nj = 0; nj < 3; ++nj)
          bfr[nj] = *(const bf16x8*)&vL[nj * 16 + lm][kh * 32 + lq * 8];
#pragma unroll
        for (int mi = 0; mi < 2; ++mi)
#pragma unroll
          for (int nj = 0; nj < 3; ++nj)
            acc[mi][nj] = __builtin_amdgcn_mfma_f32_16x16x32_bf16(af[mi], bfr[nj], acc[mi][nj], 0, 0, 0);
      }
    }
    if (t < 96) {
#pragma unroll
      for (int nn = 0; nn < 64; nn += 4) {
        const ushort4 kq4 = *(const ushort4*)&kkL[t][nn];
        ksum += (bf2f(kq4.x) + bf2f(kq4.y)) + (bf2f(kq4.z) + bf2f(kq4.w));
      }
    }
    __syncthreads();
  }
  const float inv_n = 1.0f / (float)NTOK;
  if (wave < 3) {
    // C/D layout: col = lane&15 (=e), row = (lane>>4)*4 + reg (=d within tile)
    const int mbase = wave * 32;
#pragma unroll
    for (int mi = 0; mi < 2; ++mi)
#pragma unroll
      for (int nj = 0; nj < 3; ++nj) {
        const f32x4 v = acc[mi][nj];
#pragma unroll
        for (int reg = 0; reg < 4; ++reg) {
          const int d = mbase + mi * 16 + lq * 4 + reg;
          const int e = nj * 16 + lm;
          atomicAdd(&kvm[(size_t)bh * 96 * 48 + d * 48 + e], v[reg] * inv_n);
        }
      }
  }
  if (t < 96) atomicAdd(&km[bh * 96 + t], ksum * inv_n);
}

// ---------------- k3: q features, z-norm, x_sim/x_opp; attn -> ksT -----------------
__global__ __launch_bounds__(256) void k3_attn(
    const u16* __restrict__ qsT, u16* __restrict__ attnT,
    const float* __restrict__ km_g, const float* __restrict__ kvm_g,
    const void* __restrict__ power_p, const int* __restrict__ flag)
{
  const bool f32 = (*flag != 0);
  __shared__ __align__(16) float kvmL[96][48];
  __shared__ float kmL[96];
  __shared__ float pw[48];
  const int bh = blockIdx.y;
  const int b = bh >> 3, h = bh & 7;
  const int t = threadIdx.x;
  for (int i = t; i < 96 * 48; i += 256) kvmL[i / 48][i % 48] = kvm_g[(size_t)bh * 96 * 48 + i];
  if (t < 96) kmL[t] = km_g[bh * 96 + t];
  if (t < 48) pw[t] = 1.0f + 4.0f / (1.0f + expf(-ldx1(power_p, h * HDIM + t, f32)));
  __syncthreads();
  const int n = blockIdx.x * 512 + t;
  const size_t chan0 = ((size_t)(b * CDIM + h * HDIM)) * NTOK + n;
  const u16* qbase = qsT + chan0;
  u16* obase = attnT + chan0;
  float4 accs[2][6] = {}, acco[2][6] = {};
  float zs[2] = {}, zo[2] = {};
  for (int d = 0; d < 48; ++d) {
    const float p = pw[d];
    float qp[2], qn[2];
#pragma unroll
    for (int i = 0; i < 2; ++i) {
      const float qv = bf2f(qbase[(size_t)d * NTOK + i * 256]);
      const float f = pow_mag(fabsf(qv), p);
      qp[i] = (qv > 0.f) ? f : 0.f;
      qn[i] = (qv < 0.f) ? f : 0.f;
      zs[i] = fmaf(qp[i], kmL[d], zs[i]); zs[i] = fmaf(qn[i], kmL[d + 48], zs[i]);
      zo[i] = fmaf(qn[i], kmL[d], zo[i]); zo[i] = fmaf(qp[i], kmL[d + 48], zo[i]);
    }
#pragma unroll
    for (int e4 = 0; e4 < 6; ++e4) {
      const float4 kvA = *(const float4*)&kvmL[d][e4 * 4];
      const float4 kvB = *(const float4*)&kvmL[d + 48][e4 * 4];
      const float4 kvC = *(const float4*)&kvmL[d][24 + e4 * 4];
      const float4 kvD = *(const float4*)&kvmL[d + 48][24 + e4 * 4];
#pragma unroll
      for (int i = 0; i < 2; ++i) {
        accs[i][e4].x = fmaf(qp[i], kvA.x, fmaf(qn[i], kvB.x, accs[i][e4].x));
        accs[i][e4].y = fmaf(qp[i], kvA.y, fmaf(qn[i], kvB.y, accs[i][e4].y));
        accs[i][e4].z = fmaf(qp[i], kvA.z, fmaf(qn[i], kvB.z, accs[i][e4].z));
        accs[i][e4].w = fmaf(qp[i], kvA.w, fmaf(qn[i], kvB.w, accs[i][e4].w));
        acco[i][e4].x = fmaf(qn[i], kvC.x, fmaf(qp[i], kvD.x, acco[i][e4].x));
        acco[i][e4].y = fmaf(qn[i], kvC.y, fmaf(qp[i], kvD.y, acco[i][e4].y));
        acco[i][e4].z = fmaf(qn[i], kvC.z, fmaf(qp[i], kvD.z, acco[i][e4].z));
        acco[i][e4].w = fmaf(qn[i], kvC.w, fmaf(qp[i], kvD.w, acco[i][e4].w));
      }
    }
  }
#pragma unroll
  for (int i = 0; i < 2; ++i) {
    const float zsi = 1.0f / (zs[i] + 1e-6f);
    const float zoi = 1.0f / (zo[i] + 1e-6f);
#pragma unroll
    for (int e4 = 0; e4 < 6; ++e4) {
      const float4 s = accs[i][e4], o = acco[i][e4];
      obase[(size_t)(e4 * 4 + 0) * NTOK + i * 256]    = f2bf(s.x * zsi);
      obase[(size_t)(e4 * 4 + 1) * NTOK + i * 256]    = f2bf(s.y * zsi);
      obase[(size_t)(e4 * 4 + 2) * NTOK + i * 256]    = f2bf(s.z * zsi);
      obase[(size_t)(e4 * 4 + 3) * NTOK + i * 256]    = f2bf(s.w * zsi);
      obase[(size_t)(24 + e4 * 4 + 0) * NTOK + i * 256] = f2bf(o.x * zoi);
      obase[(size_t)(24 + e4 * 4 + 1) * NTOK + i * 256] = f2bf(o.y * zoi);
      obase[(size_t)(24 + e4 * 4 + 2) * NTOK + i * 256] = f2bf(o.z * zoi);
      obase[(size_t)(24 + e4 * 4 + 3) * NTOK + i * 256] = f2bf(o.w * zoi);
    }
  }
}

// ---------------- k4: 5x5 depthwise conv on vT + out2 = (attn + conv) * g ----------
// R14: halo baked into tile [20][136] (col = gx+4, zero-padded); 4 outputs per
// thread via 3 aligned float4 reads + register-shifted stencil; ushort4 RMW.
__global__ __launch_bounds__(256) void k4_conv_combine(
    const u16* __restrict__ vT, const u16* __restrict__ gT,
    const void* __restrict__ dwc_w, const void* __restrict__ dwc_b,
    const int* __restrict__ flag,
    u16* __restrict__ attnT)
{
  const bool f32 = (*flag != 0);
  __shared__ float tile[20][136];
  const int bc = blockIdx.y;
  const int y0 = blockIdx.x * 16;
  const int t = threadIdx.x;
  const int d = bc % 48;
  float w[25];
#pragma unroll
  for (int i = 0; i < 25; ++i) w[i] = ldx1(dwc_w, d * 25 + i, f32);
  const float bias = ldx1(dwc_b, d, f32);
  const u16* vimg = vT + (size_t)bc * NTOK;
  for (int i = t; i < 20 * 34; i += 256) {
    const int r = i / 34, cq = (i - r * 34) * 4;   // tile col group (gx = col-4)
    const int gy = y0 + r - 2;
    float4 v4 = make_float4(0.f, 0.f, 0.f, 0.f);
    if (gy >= 0 && gy < IMGH) {
      const int gx0 = cq - 4;
      if (gx0 >= 0 && gx0 + 3 < IMGW) {
        const ushort4 u = *(const ushort4*)(vimg + gy * IMGW + gx0);
        v4 = make_float4(bf2f(u.x), bf2f(u.y), bf2f(u.z), bf2f(u.w));
      } else {
#pragma unroll
        for (int jj = 0; jj < 4; ++jj) {
          const int gx = gx0 + jj;
          ((float*)&v4)[jj] = (gx >= 0 && gx < IMGW) ? bf2f(vimg[gy * IMGW + gx]) : 0.f;
        }
      }
    }
    *(float4*)&tile[r][cq] = v4;
  }
  __syncthreads();
  u16* abase = attnT + (size_t)bc * NTOK;
  const u16* gbase = gT + (size_t)bc * NTOK;
#pragma unroll
  for (int pass = 0; pass < 2; ++pass) {
    const int yy = pass * 8 + (t >> 5);         // 0..15
    const int x0 = (t & 31) * 4;                // 0..124
    float a0 = bias, a1 = bias, a2 = bias, a3 = bias;
#pragma unroll
    for (int dy = 0; dy < 5; ++dy) {
      const float* row = &tile[yy + dy][0];
      const float4 A = *(const float4*)&row[x0];       // gx x0-4..x0-1
      const float4 B = *(const float4*)&row[x0 + 4];   // gx x0..x0+3
      const float4 C = *(const float4*)&row[x0 + 8];   // gx x0+4..x0+7
      const float c0 = A.z, c1 = A.w, c2 = B.x, c3 = B.y,
                  c4 = B.z, c5 = B.w, c6 = C.x, c7 = C.y;
      const float w0 = w[dy * 5 + 0], w1 = w[dy * 5 + 1], w2 = w[dy * 5 + 2],
                  w3 = w[dy * 5 + 3], w4 = w[dy * 5 + 4];
      a0 = fmaf(w0, c0, fmaf(w1, c1, fmaf(w2, c2, fmaf(w3, c3, fmaf(w4, c4, a0)))));
      a1 = fmaf(w0, c1, fmaf(w1, c2, fmaf(w2, c3, fmaf(w3, c4, fmaf(w4, c5, a1)))));
      a2 = fmaf(w0, c2, fmaf(w1, c3, fmaf(w2, c4, fmaf(w3, c5, fmaf(w4, c6, a2)))));
      a3 = fmaf(w0, c3, fmaf(w1, c4, fmaf(w2, c5, fmaf(w3, c6, fmaf(w4, c7, a3)))));
    }
    const int gidx = (y0 + yy) * IMGW + x0;
    const ushort4 at = *(const ushort4*)(abase + gidx);
    const ushort4 gg = *(const ushort4*)(gbase + gidx);
    *(ushort4*)(abase + gidx) = make_ushort4(
        f2bf((bf2f(at.x) + a0) * bf2f(gg.x)),
        f2bf((bf2f(at.y) + a1) * bf2f(gg.y)),
        f2bf((bf2f(at.z) + a2) * bf2f(gg.z)),
        f2bf((bf2f(at.w) + a3) * bf2f(gg.w)));
  }
}

// ---------------- k4b: transpose out2 channel-major -> token-major -----------------
__global__ __launch_bounds__(256) void k4b_transpose(
    const u16* __restrict__ src,   // [(b*384+c)][n]
    u16* __restrict__ dst)         // [(b*16384+n)][c]
{
  __shared__ u16 tile[64][68];
  const int b  = blockIdx.z;
  const int c0 = blockIdx.y * 64;
  const int n0 = blockIdx.x * 64;
  const int t = threadIdx.x;
  const int tr = t >> 4, tq = t & 15;
#pragma unroll
  for (int i = 0; i < 4; ++i) {
    const int r = tr + i * 16;     // c-row
    *(ushort4*)&tile[r][tq * 4] =
        *(const ushort4*)(src + ((size_t)(b * CDIM + c0 + r)) * NTOK + n0 + tq * 4);
  }
  __syncthreads();
#pragma unroll
  for (int i = 0; i < 4; ++i) {
    const int n = tr + i * 16;     // token-row
    const ushort4 vv = make_ushort4(tile[tq * 4 + 0][n], tile[tq * 4 + 1][n],
                                    tile[tq * 4 + 2][n], tile[tq * 4 + 3][n]);
    *(ushort4*)(dst + ((size_t)(b * NTOK + n0 + n)) * CDIM + c0 + tq * 4) = vv;
  }
}

// ---------------- k5: MFMA GEMM out2_tm @ Wproj + b -> d_out -----------------------
// T3 2-phase dbuf K-loop (R9); coalesced fp32 epilogue via LDS (2 passes).
__global__ __launch_bounds__(256) void k5_mfma(
    const u16* __restrict__ A,     // [row=b*16384+n][c] bf16
    const u16* __restrict__ WpT,   // [c_out][c_in] bf16
    const void* __restrict__ bp, const int* __restrict__ flag,
    void* __restrict__ out)
{
  const bool f32 = (*flag != 0);
  // flat 64KB: A dbuf [0..16384), B dbuf [16384..32768) u16.
  // epilogue overlays first 33.8KB as float ef[64][132].
  __shared__ __align__(16) u16 smem[32768];
  u16* Asm0 = smem;
  u16* Asm1 = smem + 8192;
  u16* Bsm0 = smem + 16384;
  u16* Bsm1 = smem + 24576;
  const int t = threadIdx.x;
  const int bid = blockIdx.x;                   // 0..1535
  const int rm = (bid & 7) * 192 + (bid >> 3);  // XCD-contiguous remap
  const int m_idx = rm / 3;
  const int n_idx = rm - m_idx * 3;
  const int n0 = n_idx * 128;                   // 0..383
  const int m0 = m_idx * 128;
  const int wave = t >> 6, lane = t & 63;
  const int wr = wave >> 1, wc = wave & 1;
  const int lm = lane & 15, lq = lane >> 4;

  f32x4 acc[4][4] = {};

  auto STAGE = [&](int buf, int k0) {
    u16* Ab = buf ? Asm1 : Asm0;
    u16* Bb = buf ? Bsm1 : Bsm0;
#pragma unroll
    for (int i = 0; i < 4; ++i) {
      const int chunk = i * 256 + t;
      const int row = chunk >> 3, c8 = chunk & 7;
      const int sc8 = c8 ^ (row & 7);           // source-side swizzle
      u16* lpA = &Ab[(i * 256 + wave * 64) * 8];
      u16* lpB = &Bb[(i * 256 + wave * 64) * 8];
      gload16(lpA, A + (size_t)(m0 + row) * CDIM + k0 + sc8 * 8);
      gload16(lpB, WpT + (size_t)(n0 + row) * CDIM + k0 + sc8 * 8);
    }
  };
  auto COMPUTE = [&](int buf) {
    u16* Ab = buf ? Asm1 : Asm0;
    u16* Bb = buf ? Bsm1 : Bsm0;
#pragma unroll
    for (int kh = 0; kh < 2; ++kh) {
      bf16x8 af[4], bfr[4];
#pragma unroll
      for (int r = 0; r < 4; ++r) {
        const int row = wr * 64 + r * 16 + lm;
        af[r] = *(const bf16x8*)&Ab[row * 64 + (((kh * 4 + lq) ^ (row & 7)) * 8)];
      }
#pragma unroll
      for (int cb = 0; cb < 4; ++cb) {
        const int row = wc * 64 + cb * 16 + lm;
        bfr[cb] = *(const bf16x8*)&Bb[row * 64 + (((kh * 4 + lq) ^ (row & 7)) * 8)];
      }
#pragma unroll
      for (int r = 0; r < 4; ++r)
#pragma unroll
        for (int cb = 0; cb < 4; ++cb)
          acc[r][cb] = __builtin_amdgcn_mfma_f32_16x16x32_bf16(af[r], bfr[cb], acc[r][cb], 0, 0, 0);
    }
  };

  STAGE(0, 0);
  asm volatile("s_waitcnt vmcnt(0)" ::: "memory");
  __builtin_amdgcn_sched_barrier(0);
  __builtin_amdgcn_s_barrier();
  int cur = 0;
#pragma unroll
  for (int ks = 0; ks < 5; ++ks) {
    STAGE(cur ^ 1, (ks + 1) * 64);
    COMPUTE(cur);
    asm volatile("s_waitcnt vmcnt(0)" ::: "memory");
    __builtin_amdgcn_sched_barrier(0);
    __builtin_amdgcn_s_barrier();
    cur ^= 1;
  }
  COMPUTE(cur);

  if (f32) {
    // ---- coalesced fp32 epilogue: 2 half-tile passes through LDS ----
    float* ef = (float*)smem;                   // 64 x 132 f32 = 33.8KB
    float bb[4];
#pragma unroll
    for (int cb = 0; cb < 4; ++cb) bb[cb] = ((const float*)bp)[n0 + wc * 64 + cb * 16 + lm];
    for (int h = 0; h < 2; ++h) {
      __syncthreads();                          // K-loop reads / prev pass done
      if (wr == h) {
#pragma unroll
        for (int cb = 0; cb < 4; ++cb) {
          const int cl = wc * 64 + cb * 16 + lm;    // 0..127
#pragma unroll
          for (int r = 0; r < 4; ++r) {
            const int tl = r * 16 + lq * 4;         // 0..63 in half-tile
            const f32x4 v = acc[r][cb];
#pragma unroll
            for (int reg = 0; reg < 4; ++reg)
              ef[(tl + reg) * 132 + cl] = v[reg] + bb[cb];
          }
        }
      }
      __syncthreads();
      // store 64 rows x 128 c: 512B contiguous per row
      float* ob = (float*)out + (size_t)(m0 + h * 64) * CDIM + n0;
#pragma unroll
      for (int i = 0; i < 8; ++i) {
        const int idx = i * 256 + t;
        const int row = idx >> 5, seg = idx & 31; // 32 x float4 per row
        const float4 val = *(const float4*)&ef[row * 132 + seg * 4];
        *(float4*)(ob + (size_t)row * CDIM + seg * 4) = val;
      }
    }
  } else {
    // bf16 out: original scattered path (rare)
#pragma unroll
    for (int cb = 0; cb < 4; ++cb) {
      const int cg = n0 + wc * 64 + cb * 16 + lm;
      const float bbs = bf2f(((const u16*)bp)[cg]);
#pragma unroll
      for (int r = 0; r < 4; ++r) {
        const int rowtok = m0 + wr * 64 + r * 16 + lq * 4;
        const f32x4 v = acc[r][cb];
#pragma unroll
        for (int reg = 0; reg < 4; ++reg) {
          const size_t o = (size_t)(rowtok + reg) * CDIM + cg;
          ((u16*)out)[o] = f2bf(v[reg] + bbs);
        }
      }
    }
  }
}

extern "C" void kernel_launch(void* const* d_in, const int* in_sizes, int n_in,
                              void* d_out, int out_size, void* d_ws, size_t ws_size,
                              hipStream_t stream) {
  const void* x       = d_in[0];
  const void* Wqg     = d_in[1];
  const void* Wkv     = d_in[2];
  const void* Wproj   = d_in[3];
  const void* bproj   = d_in[4];
  const void* pos_enc = d_in[5];
  const void* power_p = d_in[6];
  const void* scale_p = d_in[7];
  const void* dwc_w   = d_in[8];
  const void* dwc_b   = d_in[9];

  const size_t S = (size_t)NB * NTOK * CDIM;                 // 25,165,824
  const size_t stats_off   = 256;
  const size_t stats_bytes = (size_t)(32 * 96 + 32 * 96 * 48) * sizeof(float);
  const size_t w2t_elems = 1536 * 384, wpt_elems = 384 * 384;
  const size_t need = stats_off + stats_bytes + 3 * S * sizeof(u16)
                    + (w2t_elems + wpt_elems) * sizeof(u16);
  if (ws_size < need) return;

  int*   flag = (int*)d_ws;
  float* km   = (float*)((char*)d_ws + stats_off);
  float* kvm  = km + 32 * 96;
  u16* qsT = (u16*)((char*)d_ws + stats_off + stats_bytes);  // q/scale; later out2_tm
  u16* gT  = qsT + S;
  u16* ksT = gT + S;                                         // k feats; attn; out2
  u16* W2T = ksT + S;
  u16* WpT = W2T + w2t_elems;
  u16* vT  = (u16*)d_out;                                    // dead before k5 writes

  // bf16 scratch for x lives in the SECOND half of d_out when out is fp32
  // (bytes [2S, 4S) -- disjoint from vT's [0, 2S); dead once k1 completes,
  // k5 overwrites the whole out buffer afterwards).
  const int conv_ok = (out_size >= (int)(S * 4)) ? 1 : 0;
  u16* xbf = conv_ok ? ((u16*)d_out + S) : (u16*)d_out;      // unused if !conv_ok

  hipMemsetAsync(km, 0, stats_bytes, stream);

  k0_detect<<<1, 256, 0, stream>>>(x, flag);
  if (conv_ok) kx_convert<<<2048, 256, 0, stream>>>(x, flag, xbf);
  kprep<<<(int)((w2t_elems + wpt_elems + 255) / 256), 256, 0, stream>>>(
      Wqg, Wkv, Wproj, flag, W2T, WpT);
  k1_mfma<<<6144, 512, 0, stream>>>(x, xbf, W2T, pos_enc, scale_p, flag, conv_ok,
                                    qsT, gT, ksT, vT);
  k2_stats<<<dim3(32, 16), 256, 0, stream>>>(ksT, vT, power_p, flag, km, kvm);
  k3_attn<<<dim3(32, 32), 256, 0, stream>>>(qsT, ksT, km, kvm, power_p, flag);
  k4_conv_combine<<<dim3(8, 1536), 256, 0, stream>>>(vT, gT, dwc_w, dwc_b, flag, ksT);
  k4b_transpose<<<dim3(256, 6, 4), 256, 0, stream>>>(ksT, qsT);
  k5_mfma<<<1536, 256, 0, stream>>>(qsT, WpT, bproj, flag, d_out);
}

// Round 16
// 662.885 us; speedup vs baseline: 1.2010x; 1.0072x over previous
//
#include <hip/hip_runtime.h>
#include <math.h>

// PolaLinearAttention, MI355X round 16: k5 -> k1's 8-wave single-buffer recipe.
// R15 post-mortem: k2 MFMA = -89us (757->668, predicted -80); pattern verified.
// Remaining big fish: k5 (~140us inferred: R10 dbuf-removal cost 32us; still
// 4 waves x 64KB LDS = 8 waves/CU) and k3 (~100us). This round: port k1's
// MEASURED R10 recipe to k5: 512 thr / 8 waves (2Mx4N, acc[4][2]), single
// 32KB staging (STAGE -> sync -> COMPUTE -> sync; inter-block overlap covers
// the drain at 4 blocks/CU = 32 waves/CU), fp32 epilogue unchanged 2-pass
// ef[64][132] (33.8KB union). Math/rounding identical. Only k5 touched;
// k1 (205us, Occ 60) = control.
// Layout: intermediates channel-major T: (b*384+c)*16384 + n (bf16).
//   qsT,gT,ksT in ws; vT in d_out (dead before k5 writes); xbf in d_out[2S,4S).
// ws: flag|stats(0.6MB)|qsT,gT,ksT(151MB)|W2T,WpT(1.5MB) ~= 154MB (guarded).

#define NB 4
#define NTOK 16384
#define CDIM 384
#define NHEAD 8
#define HDIM 48
#define IMGH 128
#define IMGW 128

typedef unsigned short u16;
typedef unsigned int u32;
typedef __attribute__((ext_vector_type(8))) short bf16x8;
typedef __attribute__((ext_vector_type(4))) float f32x4;

__device__ __forceinline__ float bf2f(u16 u) {
  return __uint_as_float(((unsigned)u) << 16);
}
__device__ __forceinline__ u16 f2bf(float f) {
  unsigned u = __float_as_uint(f);
  u += 0x7FFF + ((u >> 16) & 1);   // RNE
  return (u16)(u >> 16);
}
// |v|^p, safe: never logs non-positive, never inf/NaN.
__device__ __forceinline__ float pow_mag(float r, float p) {
  if (r < 1e-20f) return 0.0f;
  return exp2f(fminf(p * log2f(r), 80.0f));
}
// dual-dtype loads for EXTERNAL tensors
__device__ __forceinline__ float ldx1(const void* p, size_t i, bool f32) {
  return f32 ? ((const float*)p)[i] : bf2f(((const u16*)p)[i]);
}
// async global->LDS 16B: LDS dest is wave-uniform base + lane*16.
__device__ __forceinline__ void gload16(u16* lds, const u16* g) {
  __builtin_amdgcn_global_load_lds(
      (const __attribute__((address_space(1))) u32*)g,
      (__attribute__((address_space(3))) u32*)lds, 16, 0, 0);
}

// ---------------- k0: dtype detector ------------------------------------------------
__global__ __launch_bounds__(256) void k0_detect(const void* __restrict__ x,
                                                 int* __restrict__ flag) {
  __shared__ int s[256];
  const u16* p = (const u16*)x;
  const int t = threadIdx.x;
  int good = 0;
#pragma unroll
  for (int i = 0; i < 16; ++i) {
    const u16 w = p[t * 16 + i];
    const int e = (w >> 7) & 0xFF;
    good += (e >= 0x60 && e <= 0x85) ? 1 : 0;   // sane bf16 exponent
  }
  s[t] = good;
  __syncthreads();
  for (int o = 128; o > 0; o >>= 1) {
    if (t < o) s[t] += s[t + o];
    __syncthreads();
  }
  if (t == 0) *flag = (s[0] >= (4096 * 4) / 5) ? 0 : 1;  // 0 = bf16, 1 = fp32
}

// ---------------- kx: one-shot x fp32 -> bf16 (only when out buffer is fp32) -------
__global__ __launch_bounds__(256) void kx_convert(const void* __restrict__ x,
                                                  const int* __restrict__ flag,
                                                  u16* __restrict__ xbf) {
  if (*flag == 0) return;                       // input already bf16
  const size_t S = (size_t)NB * NTOK * CDIM;
  const size_t tid = (size_t)blockIdx.x * 256 + threadIdx.x;
  const size_t stride = (size_t)gridDim.x * 256;
  const float4* xf = (const float4*)x;
  for (size_t i = tid; i < S / 8; i += stride) {
    const float4 a = xf[i * 2 + 0];
    const float4 b = xf[i * 2 + 1];
    *(ushort4*)(xbf + i * 8 + 0) = make_ushort4(f2bf(a.x), f2bf(a.y), f2bf(a.z), f2bf(a.w));
    *(ushort4*)(xbf + i * 8 + 4) = make_ushort4(f2bf(b.x), f2bf(b.y), f2bf(b.z), f2bf(b.w));
  }
}

// ---------------- kprep: bf16 transposed weights -----------------------------------
__global__ __launch_bounds__(256) void kprep(
    const void* __restrict__ Wqg, const void* __restrict__ Wkv,
    const void* __restrict__ Wp, const int* __restrict__ flag,
    u16* __restrict__ W2T, u16* __restrict__ WpT)
{
  const bool f32 = (*flag != 0);
  const int idx = blockIdx.x * 256 + threadIdx.x;
  if (idx < 1536 * 384) {
    const int n = idx / 384, k = idx - n * 384;
    const float v = (n < 768) ? ldx1(Wqg, (size_t)k * 768 + n, f32)
                              : ldx1(Wkv, (size_t)k * 768 + (n - 768), f32);
    W2T[idx] = f2bf(v);
  } else {
    const int j = idx - 1536 * 384;
    if (j < 384 * 384) {
      const int n = j / 384, k = j - n * 384;
      WpT[j] = f2bf(ldx1(Wp, (size_t)k * 384 + n, f32));
    }
  }
}

// ---------------- k1: MFMA GEMM x @ [Wqg|Wkv] -> qsT,gT,ksT,vT ---------------------
// 128(M tok) x 128(N ch) tile, BK=64, 8 waves (2M x 4N, each 64tok x 32ch).
// Single-buffered staging (34KB block LDS -> 4 blocks/CU); coalesced epilogue.
__global__ __launch_bounds__(512) void k1_mfma(
    const void* __restrict__ x, const u16* __restrict__ xbf,
    const u16* __restrict__ W2T,
    const void* __restrict__ pos_enc, const void* __restrict__ scale_p,
    const int* __restrict__ flag, const int conv_ok,
    u16* __restrict__ qsT, u16* __restrict__ gT, u16* __restrict__ ksT, u16* __restrict__ vT)
{
  const bool f32 = (*flag != 0);
  const bool fast = (!f32) || (conv_ok != 0);   // bf16 source available
  const u16* Asrc = f32 ? xbf : (const u16*)x;
  // 34KB union: staging A[0..8191] + B[8192..16383]; epilogue et[0..17407].
  __shared__ __align__(16) u16 smem[17408];
  u16* Asm = smem;                              // [128][64] u16, XOR-swz contents
  u16* Bsm = smem + 8192;                       // [128][64]
  const int t = threadIdx.x;
  const int bid = blockIdx.x;                   // 0..6143
  const int rm = (bid & 7) * 768 + (bid >> 3);  // XCD-contiguous remap
  const int m_idx = rm / 12;
  const int n_idx = rm - m_idx * 12;
  const int n0 = n_idx * 128;                   // 0..1535
  const int m0 = m_idx * 128;                   // 0..65535
  const int wave = t >> 6, lane = t & 63;
  const int wr = wave >> 2, wc = wave & 3;      // 2M x 4N
  const int lm = lane & 15, lq = lane >> 4;

  f32x4 acc[4][2] = {};

  // stage one 128x64 A-tile + B-tile (2+2 gload16/thread)
  auto STAGE = [&](int k0) {
#pragma unroll
    for (int i = 0; i < 2; ++i) {
      const int chunk = i * 512 + t;            // 0..1023 chunks of 8 u16
      const int row = chunk >> 3, c8 = chunk & 7;
      const int sc8 = c8 ^ (row & 7);           // source-side swizzle
      u16* lpA = &Asm[(i * 512 + wave * 64) * 8];   // wave-uniform base
      u16* lpB = &Bsm[(i * 512 + wave * 64) * 8];
      gload16(lpA, Asrc + (size_t)(m0 + row) * CDIM + k0 + sc8 * 8);
      gload16(lpB, W2T + (size_t)(n0 + row) * CDIM + k0 + sc8 * 8);
    }
  };
  auto COMPUTE = [&]() {
#pragma unroll
    for (int kh = 0; kh < 2; ++kh) {
      bf16x8 af[4], bfr[2];
#pragma unroll
      for (int r = 0; r < 4; ++r) {
        const int row = wr * 64 + r * 16 + lm;
        af[r] = *(const bf16x8*)&Asm[row * 64 + (((kh * 4 + lq) ^ (row & 7)) * 8)];
      }
#pragma unroll
      for (int cb = 0; cb < 2; ++cb) {
        const int row = wc * 32 + cb * 16 + lm;
        bfr[cb] = *(const bf16x8*)&Bsm[row * 64 + (((kh * 4 + lq) ^ (row & 7)) * 8)];
      }
#pragma unroll
      for (int r = 0; r < 4; ++r)
#pragma unroll
        for (int cb = 0; cb < 2; ++cb)
          acc[r][cb] = __builtin_amdgcn_mfma_f32_16x16x32_bf16(af[r], bfr[cb], acc[r][cb], 0, 0, 0);
    }
  };

  if (fast) {
    for (int ks = 0; ks < 6; ++ks) {
      STAGE(ks * 64);
      __syncthreads();                          // drains vmcnt -> tile landed
      COMPUTE();
      __syncthreads();                          // reads done before next STAGE
    }
  } else {
    // fallback: fp32 input but no bf16 scratch (out buffer too small)
    for (int k0 = 0; k0 < CDIM; k0 += 64) {
#pragma unroll
      for (int i = 0; i < 2; ++i) {
        const int chunk = t + i * 512;
        const int row = chunk >> 3, c8 = chunk & 7;
        const int ldsoff = row * 64 + ((c8 ^ (row & 7)) * 8);
        const float* xp = (const float*)x + (size_t)(m0 + row) * CDIM + k0 + c8 * 8;
        const float4 v0 = *(const float4*)xp;
        const float4 v1 = *(const float4*)(xp + 4);
        *(ushort4*)&Asm[ldsoff]     = make_ushort4(f2bf(v0.x), f2bf(v0.y), f2bf(v0.z), f2bf(v0.w));
        *(ushort4*)&Asm[ldsoff + 4] = make_ushort4(f2bf(v1.x), f2bf(v1.y), f2bf(v1.z), f2bf(v1.w));
        *(uint4*)&Bsm[ldsoff] = *(const uint4*)(W2T + (size_t)(n0 + row) * CDIM + k0 + c8 * 8);
      }
      __syncthreads();
      COMPUTE();
      __syncthreads();
    }
  }

  // ---- epilogue: regs -> LDS [128ch][136] u16 -> coalesced 16B stores ----
  u16* et = smem;                               // 128 x 136 u16 = 34KB
  const int b = m0 >> 14;
  const int TOK0 = m0 & (NTOK - 1);
  const int region = n0 / CDIM;                 // uniform per block (384 = 3*128)
#pragma unroll
  for (int cb = 0; cb < 2; ++cb) {
    const int cl = wc * 32 + cb * 16 + lm;      // local channel 0..127
    const int c = (n0 - region * CDIM) + cl;    // 0..383
    float inv = 1.0f;
    if (region == 0 || region == 2) inv = 1.0f / log1pf(expf(ldx1(scale_p, c, f32)));
#pragma unroll
    for (int r = 0; r < 4; ++r) {
      const int tl = wr * 64 + r * 16 + lq * 4; // local token 0..127
      const f32x4 v = acc[r][cb];
      ushort4 w;
      if (region == 2) {
        const int tok = TOK0 + tl;
        const float p0 = ldx1(pos_enc, (size_t)(tok + 0) * CDIM + c, f32);
        const float p1 = ldx1(pos_enc, (size_t)(tok + 1) * CDIM + c, f32);
        const float p2 = ldx1(pos_enc, (size_t)(tok + 2) * CDIM + c, f32);
        const float p3 = ldx1(pos_enc, (size_t)(tok + 3) * CDIM + c, f32);
        w = make_ushort4(f2bf((v[0] + p0) * inv), f2bf((v[1] + p1) * inv),
                         f2bf((v[2] + p2) * inv), f2bf((v[3] + p3) * inv));
      } else if (region == 0) {
        w = make_ushort4(f2bf(v[0] * inv), f2bf(v[1] * inv), f2bf(v[2] * inv), f2bf(v[3] * inv));
      } else {
        w = make_ushort4(f2bf(v[0]), f2bf(v[1]), f2bf(v[2]), f2bf(v[3]));
      }
      *(ushort4*)&et[cl * 136 + tl] = w;
    }
  }
  __syncthreads();
  u16* dst = (region == 0) ? qsT : (region == 1) ? gT : (region == 2) ? ksT : vT;
  const int cbase = b * CDIM + (n0 - region * CDIM);
#pragma unroll
  for (int i = 0; i < 4; ++i) {
    const int idx = i * 512 + t;
    const int row = idx >> 4, seg = idx & 15;   // row = channel, seg = 16B chunk
    const uint4 val = *(const uint4*)&et[row * 136 + seg * 8];
    *(uint4*)(dst + ((size_t)(cbase + row)) * NTOK + TOK0 + seg * 8) = val;
  }
}

// ---------------- k2: per (b,h): km[96] = mean(kk), kvm[96][48] = kk^T v / N -------
// R15: MFMA. Features bf16 in LDS ([96][72],[48][72]); waves 0-2 own 32-row
// M-slabs x 3 N-tiles: 12 mfma_16x16x32_bf16 + 10 b128 per K=64 tile.
__global__ __launch_bounds__(256) void k2_stats(
    const u16* __restrict__ ksT, const u16* __restrict__ vT,
    const void* __restrict__ power_p, const int* __restrict__ flag,
    float* __restrict__ km, float* __restrict__ kvm)
{
  const bool f32 = (*flag != 0);
  __shared__ __align__(16) u16 kkL[96][72];   // bf16 features (stride 144B, 16B-aligned)
  __shared__ __align__(16) u16 vL[48][72];    // bf16 v
  __shared__ float pw[48];
  const int bh = blockIdx.x;
  const int b = bh >> 3, h = bh & 7;
  const int t = threadIdx.x;
  if (t < 48) pw[t] = 1.0f + 4.0f / (1.0f + expf(-ldx1(power_p, h * HDIM + t, f32)));
  __syncthreads();
  const int wave = t >> 6, lane = t & 63;
  const int lm = lane & 15, lq = lane >> 4;
  f32x4 acc[2][3] = {};                       // waves 0..2: [M-tile][N-tile]
  float ksum = 0.0f;
  const u16* ksbase = ksT + ((size_t)(b * CDIM + h * HDIM)) * NTOK;
  const u16* vbase  = vT  + ((size_t)(b * CDIM + h * HDIM)) * NTOK;
  const int n0base = blockIdx.y * 1024;
  for (int tile = 0; tile < 16; ++tile) {
    const int n0 = n0base + tile * 64;
    for (int i = t; i < 48 * 16; i += 256) {
      const int c = i >> 4, qd = (i & 15) * 4;
      ushort4 kq = *(const ushort4*)(ksbase + (size_t)c * NTOK + n0 + qd);
      ushort4 vq = *(const ushort4*)(vbase  + (size_t)c * NTOK + n0 + qd);
      const float p = pw[c];
      float kf[4] = {bf2f(kq.x), bf2f(kq.y), bf2f(kq.z), bf2f(kq.w)};
      ushort4 pos, neg;
#pragma unroll
      for (int jj = 0; jj < 4; ++jj) {
        const float f = pow_mag(fabsf(kf[jj]), p);
        ((u16*)&pos)[jj] = f2bf((kf[jj] > 0.f) ? f : 0.f);
        ((u16*)&neg)[jj] = f2bf((kf[jj] < 0.f) ? f : 0.f);
      }
      *(ushort4*)&kkL[c][qd]      = pos;
      *(ushort4*)&kkL[c + 48][qd] = neg;
      *(ushort4*)&vL[c][qd]       = vq;       // already bf16
    }
    __syncthreads();
    if (wave < 3) {
      const int mbase = wave * 32;
#pragma unroll
      for (int kh = 0; kh < 2; ++kh) {
        bf16x8 af[2], bfr[3];
#pragma unroll
        for (int mi = 0; mi < 2; ++mi)
          af[mi] = *(const bf16x8*)&kkL[mbase + mi * 16 + lm][kh * 32 + lq * 8];
#pragma unroll
        for (int nj = 0; nj < 3; ++nj)
          bfr[nj] = *(const bf16x8*)&vL[nj * 16 + lm][kh * 32 + lq * 8];
#pragma unroll
        for (int mi = 0; mi < 2; ++mi)
#pragma unroll
          for (int nj = 0; nj < 3; ++nj)
            acc[mi][nj] = __builtin_amdgcn_mfma_f32_16x16x32_bf16(af[mi], bfr[nj], acc[mi][nj], 0, 0, 0);
      }
    }
    if (t < 96) {
#pragma unroll
      for (int nn = 0; nn < 64; nn += 4) {
        const ushort4 kq4 = *(const ushort4*)&kkL[t][nn];
        ksum += (bf2f(kq4.x) + bf2f(kq4.y)) + (bf2f(kq4.z) + bf2f(kq4.w));
      }
    }
    __syncthreads();
  }
  const float inv_n = 1.0f / (float)NTOK;
  if (wave < 3) {
    // C/D layout: col = lane&15 (=e), row = (lane>>4)*4 + reg (=d within tile)
    const int mbase = wave * 32;
#pragma unroll
    for (int mi = 0; mi < 2; ++mi)
#pragma unroll
      for (int nj = 0; nj < 3; ++nj) {
        const f32x4 v = acc[mi][nj];
#pragma unroll
        for (int reg = 0; reg < 4; ++reg) {
          const int d = mbase + mi * 16 + lq * 4 + reg;
          const int e = nj * 16 + lm;
          atomicAdd(&kvm[(size_t)bh * 96 * 48 + d * 48 + e], v[reg] * inv_n);
        }
      }
  }
  if (t < 96) atomicAdd(&km[bh * 96 + t], ksum * inv_n);
}

// ---------------- k3: q features, z-norm, x_sim/x_opp; attn -> ksT -----------------
__global__ __launch_bounds__(256) void k3_attn(
    const u16* __restrict__ qsT, u16* __restrict__ attnT,
    const float* __restrict__ km_g, const float* __restrict__ kvm_g,
    const void* __restrict__ power_p, const int* __restrict__ flag)
{
  const bool f32 = (*flag != 0);
  __shared__ __align__(16) float kvmL[96][48];
  __shared__ float kmL[96];
  __shared__ float pw[48];
  const int bh = blockIdx.y;
  const int b = bh >> 3, h = bh & 7;
  const int t = threadIdx.x;
  for (int i = t; i < 96 * 48; i += 256) kvmL[i / 48][i % 48] = kvm_g[(size_t)bh * 96 * 48 + i];
  if (t < 96) kmL[t] = km_g[bh * 96 + t];
  if (t < 48) pw[t] = 1.0f + 4.0f / (1.0f + expf(-ldx1(power_p, h * HDIM + t, f32)));
  __syncthreads();
  const int n = blockIdx.x * 512 + t;
  const size_t chan0 = ((size_t)(b * CDIM + h * HDIM)) * NTOK + n;
  const u16* qbase = qsT + chan0;
  u16* obase = attnT + chan0;
  float4 accs[2][6] = {}, acco[2][6] = {};
  float zs[2] = {}, zo[2] = {};
  for (int d = 0; d < 48; ++d) {
    const float p = pw[d];
    float qp[2], qn[2];
#pragma unroll
    for (int i = 0; i < 2; ++i) {
      const float qv = bf2f(qbase[(size_t)d * NTOK + i * 256]);
      const float f = pow_mag(fabsf(qv), p);
      qp[i] = (qv > 0.f) ? f : 0.f;
      qn[i] = (qv < 0.f) ? f : 0.f;
      zs[i] = fmaf(qp[i], kmL[d], zs[i]); zs[i] = fmaf(qn[i], kmL[d + 48], zs[i]);
      zo[i] = fmaf(qn[i], kmL[d], zo[i]); zo[i] = fmaf(qp[i], kmL[d + 48], zo[i]);
    }
#pragma unroll
    for (int e4 = 0; e4 < 6; ++e4) {
      const float4 kvA = *(const float4*)&kvmL[d][e4 * 4];
      const float4 kvB = *(const float4*)&kvmL[d + 48][e4 * 4];
      const float4 kvC = *(const float4*)&kvmL[d][24 + e4 * 4];
      const float4 kvD = *(const float4*)&kvmL[d + 48][24 + e4 * 4];
#pragma unroll
      for (int i = 0; i < 2; ++i) {
        accs[i][e4].x = fmaf(qp[i], kvA.x, fmaf(qn[i], kvB.x, accs[i][e4].x));
        accs[i][e4].y = fmaf(qp[i], kvA.y, fmaf(qn[i], kvB.y, accs[i][e4].y));
        accs[i][e4].z = fmaf(qp[i], kvA.z, fmaf(qn[i], kvB.z, accs[i][e4].z));
        accs[i][e4].w = fmaf(qp[i], kvA.w, fmaf(qn[i], kvB.w, accs[i][e4].w));
        acco[i][e4].x = fmaf(qn[i], kvC.x, fmaf(qp[i], kvD.x, acco[i][e4].x));
        acco[i][e4].y = fmaf(qn[i], kvC.y, fmaf(qp[i], kvD.y, acco[i][e4].y));
        acco[i][e4].z = fmaf(qn[i], kvC.z, fmaf(qp[i], kvD.z, acco[i][e4].z));
        acco[i][e4].w = fmaf(qn[i], kvC.w, fmaf(qp[i], kvD.w, acco[i][e4].w));
      }
    }
  }
#pragma unroll
  for (int i = 0; i < 2; ++i) {
    const float zsi = 1.0f / (zs[i] + 1e-6f);
    const float zoi = 1.0f / (zo[i] + 1e-6f);
#pragma unroll
    for (int e4 = 0; e4 < 6; ++e4) {
      const float4 s = accs[i][e4], o = acco[i][e4];
      obase[(size_t)(e4 * 4 + 0) * NTOK + i * 256]    = f2bf(s.x * zsi);
      obase[(size_t)(e4 * 4 + 1) * NTOK + i * 256]    = f2bf(s.y * zsi);
      obase[(size_t)(e4 * 4 + 2) * NTOK + i * 256]    = f2bf(s.z * zsi);
      obase[(size_t)(e4 * 4 + 3) * NTOK + i * 256]    = f2bf(s.w * zsi);
      obase[(size_t)(24 + e4 * 4 + 0) * NTOK + i * 256] = f2bf(o.x * zoi);
      obase[(size_t)(24 + e4 * 4 + 1) * NTOK + i * 256] = f2bf(o.y * zoi);
      obase[(size_t)(24 + e4 * 4 + 2) * NTOK + i * 256] = f2bf(o.z * zoi);
      obase[(size_t)(24 + e4 * 4 + 3) * NTOK + i * 256] = f2bf(o.w * zoi);
    }
  }
}

// ---------------- k4: 5x5 depthwise conv on vT + out2 = (attn + conv) * g ----------
// R14: halo baked into tile [20][136] (col = gx+4, zero-padded); 4 outputs per
// thread via 3 aligned float4 reads + register-shifted stencil; ushort4 RMW.
__global__ __launch_bounds__(256) void k4_conv_combine(
    const u16* __restrict__ vT, const u16* __restrict__ gT,
    const void* __restrict__ dwc_w, const void* __restrict__ dwc_b,
    const int* __restrict__ flag,
    u16* __restrict__ attnT)
{
  const bool f32 = (*flag != 0);
  __shared__ float tile[20][136];
  const int bc = blockIdx.y;
  const int y0 = blockIdx.x * 16;
  const int t = threadIdx.x;
  const int d = bc % 48;
  float w[25];
#pragma unroll
  for (int i = 0; i < 25; ++i) w[i] = ldx1(dwc_w, d * 25 + i, f32);
  const float bias = ldx1(dwc_b, d, f32);
  const u16* vimg = vT + (size_t)bc * NTOK;
  for (int i = t; i < 20 * 34; i += 256) {
    const int r = i / 34, cq = (i - r * 34) * 4;   // tile col group (gx = col-4)
    const int gy = y0 + r - 2;
    float4 v4 = make_float4(0.f, 0.f, 0.f, 0.f);
    if (gy >= 0 && gy < IMGH) {
      const int gx0 = cq - 4;
      if (gx0 >= 0 && gx0 + 3 < IMGW) {
        const ushort4 u = *(const ushort4*)(vimg + gy * IMGW + gx0);
        v4 = make_float4(bf2f(u.x), bf2f(u.y), bf2f(u.z), bf2f(u.w));
      } else {
#pragma unroll
        for (int jj = 0; jj < 4; ++jj) {
          const int gx = gx0 + jj;
          ((float*)&v4)[jj] = (gx >= 0 && gx < IMGW) ? bf2f(vimg[gy * IMGW + gx]) : 0.f;
        }
      }
    }
    *(float4*)&tile[r][cq] = v4;
  }
  __syncthreads();
  u16* abase = attnT + (size_t)bc * NTOK;
  const u16* gbase = gT + (size_t)bc * NTOK;
#pragma unroll
  for (int pass = 0; pass < 2; ++pass) {
    const int yy = pass * 8 + (t >> 5);         // 0..15
    const int x0 = (t & 31) * 4;                // 0..124
    float a0 = bias, a1 = bias, a2 = bias, a3 = bias;
#pragma unroll
    for (int dy = 0; dy < 5; ++dy) {
      const float* row = &tile[yy + dy][0];
      const float4 A = *(const float4*)&row[x0];       // gx x0-4..x0-1
      const float4 B = *(const float4*)&row[x0 + 4];   // gx x0..x0+3
      const float4 C = *(const float4*)&row[x0 + 8];   // gx x0+4..x0+7
      const float c0 = A.z, c1 = A.w, c2 = B.x, c3 = B.y,
                  c4 = B.z, c5 = B.w, c6 = C.x, c7 = C.y;
      const float w0 = w[dy * 5 + 0], w1 = w[dy * 5 + 1], w2 = w[dy * 5 + 2],
                  w3 = w[dy * 5 + 3], w4 = w[dy * 5 + 4];
      a0 = fmaf(w0, c0, fmaf(w1, c1, fmaf(w2, c2, fmaf(w3, c3, fmaf(w4, c4, a0)))));
      a1 = fmaf(w0, c1, fmaf(w1, c2, fmaf(w2, c3, fmaf(w3, c4, fmaf(w4, c5, a1)))));
      a2 = fmaf(w0, c2, fmaf(w1, c3, fmaf(w2, c4, fmaf(w3, c5, fmaf(w4, c6, a2)))));
      a3 = fmaf(w0, c3, fmaf(w1, c4, fmaf(w2, c5, fmaf(w3, c6, fmaf(w4, c7, a3)))));
    }
    const int gidx = (y0 + yy) * IMGW + x0;
    const ushort4 at = *(const ushort4*)(abase + gidx);
    const ushort4 gg = *(const ushort4*)(gbase + gidx);
    *(ushort4*)(abase + gidx) = make_ushort4(
        f2bf((bf2f(at.x) + a0) * bf2f(gg.x)),
        f2bf((bf2f(at.y) + a1) * bf2f(gg.y)),
        f2bf((bf2f(at.z) + a2) * bf2f(gg.z)),
        f2bf((bf2f(at.w) + a3) * bf2f(gg.w)));
  }
}

// ---------------- k4b: transpose out2 channel-major -> token-major -----------------
__global__ __launch_bounds__(256) void k4b_transpose(
    const u16* __restrict__ src,   // [(b*384+c)][n]
    u16* __restrict__ dst)         // [(b*16384+n)][c]
{
  __shared__ u16 tile[64][68];
  const int b  = blockIdx.z;
  const int c0 = blockIdx.y * 64;
  const int n0 = blockIdx.x * 64;
  const int t = threadIdx.x;
  const int tr = t >> 4, tq = t & 15;
#pragma unroll
  for (int i = 0; i < 4; ++i) {
    const int r = tr + i * 16;     // c-row
    *(ushort4*)&tile[r][tq * 4] =
        *(const ushort4*)(src + ((size_t)(b * CDIM + c0 + r)) * NTOK + n0 + tq * 4);
  }
  __syncthreads();
#pragma unroll
  for (int i = 0; i < 4; ++i) {
    const int n = tr + i * 16;     // token-row
    const ushort4 vv = make_ushort4(tile[tq * 4 + 0][n], tile[tq * 4 + 1][n],
                                    tile[tq * 4 + 2][n], tile[tq * 4 + 3][n]);
    *(ushort4*)(dst + ((size_t)(b * NTOK + n0 + n)) * CDIM + c0 + tq * 4) = vv;
  }
}

// ---------------- k5: MFMA GEMM out2_tm @ Wproj + b -> d_out -----------------------
// R16: k1's recipe. 512 thr / 8 waves (2M x 4N, acc[4][2]); single 32KB
// staging, STAGE -> sync -> COMPUTE -> sync; 34KB union -> 4 blocks/CU.
// fp32 epilogue: 2-pass ef[64][132] (one wr-half per pass), 512B row stores.
__global__ __launch_bounds__(512) void k5_mfma(
    const u16* __restrict__ A,     // [row=b*16384+n][c] bf16
    const u16* __restrict__ WpT,   // [c_out][c_in] bf16
    const void* __restrict__ bp, const int* __restrict__ flag,
    void* __restrict__ out)
{
  const bool f32 = (*flag != 0);
  // 34KB union: staging A[0..8191] + B[8192..16383] u16; epilogue ef 33.8KB.
  __shared__ __align__(16) u16 smem[17408];
  u16* Asm = smem;
  u16* Bsm = smem + 8192;
  const int t = threadIdx.x;
  const int bid = blockIdx.x;                   // 0..1535
  const int rm = (bid & 7) * 192 + (bid >> 3);  // XCD-contiguous remap
  const int m_idx = rm / 3;
  const int n_idx = rm - m_idx * 3;
  const int n0 = n_idx * 128;                   // 0..383
  const int m0 = m_idx * 128;
  const int wave = t >> 6, lane = t & 63;
  const int wr = wave >> 2, wc = wave & 3;      // 2M x 4N
  const int lm = lane & 15, lq = lane >> 4;

  f32x4 acc[4][2] = {};

  auto STAGE = [&](int k0) {
#pragma unroll
    for (int i = 0; i < 2; ++i) {
      const int chunk = i * 512 + t;
      const int row = chunk >> 3, c8 = chunk & 7;
      const int sc8 = c8 ^ (row & 7);           // source-side swizzle
      u16* lpA = &Asm[(i * 512 + wave * 64) * 8];
      u16* lpB = &Bsm[(i * 512 + wave * 64) * 8];
      gload16(lpA, A + (size_t)(m0 + row) * CDIM + k0 + sc8 * 8);
      gload16(lpB, WpT + (size_t)(n0 + row) * CDIM + k0 + sc8 * 8);
    }
  };
  auto COMPUTE = [&]() {
#pragma unroll
    for (int kh = 0; kh < 2; ++kh) {
      bf16x8 af[4], bfr[2];
#pragma unroll
      for (int r = 0; r < 4; ++r) {
        const int row = wr * 64 + r * 16 + lm;
        af[r] = *(const bf16x8*)&Asm[row * 64 + (((kh * 4 + lq) ^ (row & 7)) * 8)];
      }
#pragma unroll
      for (int cb = 0; cb < 2; ++cb) {
        const int row = wc * 32 + cb * 16 + lm;
        bfr[cb] = *(const bf16x8*)&Bsm[row * 64 + (((kh * 4 + lq) ^ (row & 7)) * 8)];
      }
#pragma unroll
      for (int r = 0; r < 4; ++r)
#pragma unroll
        for (int cb = 0; cb < 2; ++cb)
          acc[r][cb] = __builtin_amdgcn_mfma_f32_16x16x32_bf16(af[r], bfr[cb], acc[r][cb], 0, 0, 0);
    }
  };

  for (int ks = 0; ks < 6; ++ks) {
    STAGE(ks * 64);
    __syncthreads();
    COMPUTE();
    __syncthreads();
  }

  if (f32) {
    // ---- coalesced fp32 epilogue: 2 half-tile passes through LDS ----
    float* ef = (float*)smem;                   // 64 x 132 f32 = 33.8KB
    float bb[2];
#pragma unroll
    for (int cb = 0; cb < 2; ++cb) bb[cb] = ((const float*)bp)[n0 + wc * 32 + cb * 16 + lm];
    for (int h = 0; h < 2; ++h) {
      __syncthreads();                          // K-loop reads / prev pass done
      if (wr == h) {
#pragma unroll
        for (int cb = 0; cb < 2; ++cb) {
          const int cl = wc * 32 + cb * 16 + lm;    // 0..127
#pragma unroll
          for (int r = 0; r < 4; ++r) {
            const int tl = r * 16 + lq * 4;         // 0..63 in half-tile
            const f32x4 v = acc[r][cb];
#pragma unroll
            for (int reg = 0; reg < 4; ++reg)
              ef[(tl + reg) * 132 + cl] = v[reg] + bb[cb];
          }
        }
      }
      __syncthreads();
      // store 64 rows x 128 c: 512B contiguous per row
      float* ob = (float*)out + (size_t)(m0 + h * 64) * CDIM + n0;
#pragma unroll
      for (int i = 0; i < 4; ++i) {
        const int idx = i * 512 + t;
        const int row = idx >> 5, seg = idx & 31; // 32 x float4 per row
        const float4 val = *(const float4*)&ef[row * 132 + seg * 4];
        *(float4*)(ob + (size_t)row * CDIM + seg * 4) = val;
      }
    }
  } else {
    // bf16 out: scattered path (rare)
#pragma unroll
    for (int cb = 0; cb < 2; ++cb) {
      const int cg = n0 + wc * 32 + cb * 16 + lm;
      const float bbs = bf2f(((const u16*)bp)[cg]);
#pragma unroll
      for (int r = 0; r < 4; ++r) {
        const int rowtok = m0 + wr * 64 + r * 16 + lq * 4;
        const f32x4 v = acc[r][cb];
#pragma unroll
        for (int reg = 0; reg < 4; ++reg) {
          const size_t o = (size_t)(rowtok + reg) * CDIM + cg;
          ((u16*)out)[o] = f2bf(v[reg] + bbs);
        }
      }
    }
  }
}

extern "C" void kernel_launch(void* const* d_in, const int* in_sizes, int n_in,
                              void* d_out, int out_size, void* d_ws, size_t ws_size,
                              hipStream_t stream) {
  const void* x       = d_in[0];
  const void* Wqg     = d_in[1];
  const void* Wkv     = d_in[2];
  const void* Wproj   = d_in[3];
  const void* bproj   = d_in[4];
  const void* pos_enc = d_in[5];
  const void* power_p = d_in[6];
  const void* scale_p = d_in[7];
  const void* dwc_w   = d_in[8];
  const void* dwc_b   = d_in[9];

  const size_t S = (size_t)NB * NTOK * CDIM;                 // 25,165,824
  const size_t stats_off   = 256;
  const size_t stats_bytes = (size_t)(32 * 96 + 32 * 96 * 48) * sizeof(float);
  const size_t w2t_elems = 1536 * 384, wpt_elems = 384 * 384;
  const size_t need = stats_off + stats_bytes + 3 * S * sizeof(u16)
                    + (w2t_elems + wpt_elems) * sizeof(u16);
  if (ws_size < need) return;

  int*   flag = (int*)d_ws;
  float* km   = (float*)((char*)d_ws + stats_off);
  float* kvm  = km + 32 * 96;
  u16* qsT = (u16*)((char*)d_ws + stats_off + stats_bytes);  // q/scale; later out2_tm
  u16* gT  = qsT + S;
  u16* ksT = gT + S;                                         // k feats; attn; out2
  u16* W2T = ksT + S;
  u16* WpT = W2T + w2t_elems;
  u16* vT  = (u16*)d_out;                                    // dead before k5 writes

  // bf16 scratch for x lives in the SECOND half of d_out when out is fp32
  // (bytes [2S, 4S) -- disjoint from vT's [0, 2S); dead once k1 completes,
  // k5 overwrites the whole out buffer afterwards).
  const int conv_ok = (out_size >= (int)(S * 4)) ? 1 : 0;
  u16* xbf = conv_ok ? ((u16*)d_out + S) : (u16*)d_out;      // unused if !conv_ok

  hipMemsetAsync(km, 0, stats_bytes, stream);

  k0_detect<<<1, 256, 0, stream>>>(x, flag);
  if (conv_ok) kx_convert<<<2048, 256, 0, stream>>>(x, flag, xbf);
  kprep<<<(int)((w2t_elems + wpt_elems + 255) / 256), 256, 0, stream>>>(
      Wqg, Wkv, Wproj, flag, W2T, WpT);
  k1_mfma<<<6144, 512, 0, stream>>>(x, xbf, W2T, pos_enc, scale_p, flag, conv_ok,
                                    qsT, gT, ksT, vT);
  k2_stats<<<dim3(32, 16), 256, 0, stream>>>(ksT, vT, power_p, flag, km, kvm);
  k3_attn<<<dim3(32, 32), 256, 0, stream>>>(qsT, ksT, km, kvm, power_p, flag);
  k4_conv_combine<<<dim3(8, 1536), 256, 0, stream>>>(vT, gT, dwc_w, dwc_b, flag, ksT);
  k4b_transpose<<<dim3(256, 6, 4), 256, 0, stream>>>(ksT, qsT);
  k5_mfma<<<1536, 512, 0, stream>>>(qsT, WpT, bproj, flag, d_out);
}

// Round 17
// 661.681 us; speedup vs baseline: 1.2032x; 1.0018x over previous
//
#include <hip/hip_runtime.h>
#include <math.h>

// PolaLinearAttention, MI355X round 17: k3 -> MFMA (3rd use of verified pattern).
// R16 post-mortem: k5 8-wave = -5us only (668->663); k5 was already near floor.
// k3 is the last VALU/LDS-instr-heavy kernel: 1152 broadcast b128/wave x 12cy
// x 16 waves/CU ~ 92us. Fold x_sim/x_opp/z_sim/z_opp into ONE GEMM:
//   q_opp[d] = q_sim[(d+48)%96]  =>  C[96][64]: [0:24)=kvm[d][e],
//   [24:48)=kvm[(d+48)%96][e], 48=km[d], 49=km[(d+48)%96], rest 0.
//   out[e<24]=acc[e]/(acc[48]+eps); out[24<=e<48]=acc[e]/(acc[49]+eps).
// Per block: (b,h) x 128 tokens; qf[128][104] bf16 feats, cmat[64][104] bf16,
// 3 K-steps x acc[2][4] mfma_16x16x32_bf16, z via small LDS, k1-style
// coalesced epilogue. One extra bf16 rounding (same class as k2's accepted).
// Only k3 touched; k1 (204us) = control. Everything else = R16.
// Layout: intermediates channel-major T: (b*384+c)*16384 + n (bf16).
// ws: flag|stats(0.6MB)|qsT,gT,ksT(151MB)|W2T,WpT(1.5MB) ~= 154MB (guarded).

#define NB 4
#define NTOK 16384
#define CDIM 384
#define NHEAD 8
#define HDIM 48
#define IMGH 128
#define IMGW 128

typedef unsigned short u16;
typedef unsigned int u32;
typedef __attribute__((ext_vector_type(8))) short bf16x8;
typedef __attribute__((ext_vector_type(4))) float f32x4;

__device__ __forceinline__ float bf2f(u16 u) {
  return __uint_as_float(((unsigned)u) << 16);
}
__device__ __forceinline__ u16 f2bf(float f) {
  unsigned u = __float_as_uint(f);
  u += 0x7FFF + ((u >> 16) & 1);   // RNE
  return (u16)(u >> 16);
}
// |v|^p, safe: never logs non-positive, never inf/NaN.
__device__ __forceinline__ float pow_mag(float r, float p) {
  if (r < 1e-20f) return 0.0f;
  return exp2f(fminf(p * log2f(r), 80.0f));
}
// dual-dtype loads for EXTERNAL tensors
__device__ __forceinline__ float ldx1(const void* p, size_t i, bool f32) {
  return f32 ? ((const float*)p)[i] : bf2f(((const u16*)p)[i]);
}
// async global->LDS 16B: LDS dest is wave-uniform base + lane*16.
__device__ __forceinline__ void gload16(u16* lds, const u16* g) {
  __builtin_amdgcn_global_load_lds(
      (const __attribute__((address_space(1))) u32*)g,
      (__attribute__((address_space(3))) u32*)lds, 16, 0, 0);
}

// ---------------- k0: dtype detector ------------------------------------------------
__global__ __launch_bounds__(256) void k0_detect(const void* __restrict__ x,
                                                 int* __restrict__ flag) {
  __shared__ int s[256];
  const u16* p = (const u16*)x;
  const int t = threadIdx.x;
  int good = 0;
#pragma unroll
  for (int i = 0; i < 16; ++i) {
    const u16 w = p[t * 16 + i];
    const int e = (w >> 7) & 0xFF;
    good += (e >= 0x60 && e <= 0x85) ? 1 : 0;   // sane bf16 exponent
  }
  s[t] = good;
  __syncthreads();
  for (int o = 128; o > 0; o >>= 1) {
    if (t < o) s[t] += s[t + o];
    __syncthreads();
  }
  if (t == 0) *flag = (s[0] >= (4096 * 4) / 5) ? 0 : 1;  // 0 = bf16, 1 = fp32
}

// ---------------- kx: one-shot x fp32 -> bf16 (only when out buffer is fp32) -------
__global__ __launch_bounds__(256) void kx_convert(const void* __restrict__ x,
                                                  const int* __restrict__ flag,
                                                  u16* __restrict__ xbf) {
  if (*flag == 0) return;                       // input already bf16
  const size_t S = (size_t)NB * NTOK * CDIM;
  const size_t tid = (size_t)blockIdx.x * 256 + threadIdx.x;
  const size_t stride = (size_t)gridDim.x * 256;
  const float4* xf = (const float4*)x;
  for (size_t i = tid; i < S / 8; i += stride) {
    const float4 a = xf[i * 2 + 0];
    const float4 b = xf[i * 2 + 1];
    *(ushort4*)(xbf + i * 8 + 0) = make_ushort4(f2bf(a.x), f2bf(a.y), f2bf(a.z), f2bf(a.w));
    *(ushort4*)(xbf + i * 8 + 4) = make_ushort4(f2bf(b.x), f2bf(b.y), f2bf(b.z), f2bf(b.w));
  }
}

// ---------------- kprep: bf16 transposed weights -----------------------------------
__global__ __launch_bounds__(256) void kprep(
    const void* __restrict__ Wqg, const void* __restrict__ Wkv,
    const void* __restrict__ Wp, const int* __restrict__ flag,
    u16* __restrict__ W2T, u16* __restrict__ WpT)
{
  const bool f32 = (*flag != 0);
  const int idx = blockIdx.x * 256 + threadIdx.x;
  if (idx < 1536 * 384) {
    const int n = idx / 384, k = idx - n * 384;
    const float v = (n < 768) ? ldx1(Wqg, (size_t)k * 768 + n, f32)
                              : ldx1(Wkv, (size_t)k * 768 + (n - 768), f32);
    W2T[idx] = f2bf(v);
  } else {
    const int j = idx - 1536 * 384;
    if (j < 384 * 384) {
      const int n = j / 384, k = j - n * 384;
      WpT[j] = f2bf(ldx1(Wp, (size_t)k * 384 + n, f32));
    }
  }
}

// ---------------- k1: MFMA GEMM x @ [Wqg|Wkv] -> qsT,gT,ksT,vT ---------------------
// 128(M tok) x 128(N ch) tile, BK=64, 8 waves (2M x 4N, each 64tok x 32ch).
// Single-buffered staging (34KB block LDS -> 4 blocks/CU); coalesced epilogue.
__global__ __launch_bounds__(512) void k1_mfma(
    const void* __restrict__ x, const u16* __restrict__ xbf,
    const u16* __restrict__ W2T,
    const void* __restrict__ pos_enc, const void* __restrict__ scale_p,
    const int* __restrict__ flag, const int conv_ok,
    u16* __restrict__ qsT, u16* __restrict__ gT, u16* __restrict__ ksT, u16* __restrict__ vT)
{
  const bool f32 = (*flag != 0);
  const bool fast = (!f32) || (conv_ok != 0);   // bf16 source available
  const u16* Asrc = f32 ? xbf : (const u16*)x;
  // 34KB union: staging A[0..8191] + B[8192..16383]; epilogue et[0..17407].
  __shared__ __align__(16) u16 smem[17408];
  u16* Asm = smem;                              // [128][64] u16, XOR-swz contents
  u16* Bsm = smem + 8192;                       // [128][64]
  const int t = threadIdx.x;
  const int bid = blockIdx.x;                   // 0..6143
  const int rm = (bid & 7) * 768 + (bid >> 3);  // XCD-contiguous remap
  const int m_idx = rm / 12;
  const int n_idx = rm - m_idx * 12;
  const int n0 = n_idx * 128;                   // 0..1535
  const int m0 = m_idx * 128;                   // 0..65535
  const int wave = t >> 6, lane = t & 63;
  const int wr = wave >> 2, wc = wave & 3;      // 2M x 4N
  const int lm = lane & 15, lq = lane >> 4;

  f32x4 acc[4][2] = {};

  // stage one 128x64 A-tile + B-tile (2+2 gload16/thread)
  auto STAGE = [&](int k0) {
#pragma unroll
    for (int i = 0; i < 2; ++i) {
      const int chunk = i * 512 + t;            // 0..1023 chunks of 8 u16
      const int row = chunk >> 3, c8 = chunk & 7;
      const int sc8 = c8 ^ (row & 7);           // source-side swizzle
      u16* lpA = &Asm[(i * 512 + wave * 64) * 8];   // wave-uniform base
      u16* lpB = &Bsm[(i * 512 + wave * 64) * 8];
      gload16(lpA, Asrc + (size_t)(m0 + row) * CDIM + k0 + sc8 * 8);
      gload16(lpB, W2T + (size_t)(n0 + row) * CDIM + k0 + sc8 * 8);
    }
  };
  auto COMPUTE = [&]() {
#pragma unroll
    for (int kh = 0; kh < 2; ++kh) {
      bf16x8 af[4], bfr[2];
#pragma unroll
      for (int r = 0; r < 4; ++r) {
        const int row = wr * 64 + r * 16 + lm;
        af[r] = *(const bf16x8*)&Asm[row * 64 + (((kh * 4 + lq) ^ (row & 7)) * 8)];
      }
#pragma unroll
      for (int cb = 0; cb < 2; ++cb) {
        const int row = wc * 32 + cb * 16 + lm;
        bfr[cb] = *(const bf16x8*)&Bsm[row * 64 + (((kh * 4 + lq) ^ (row & 7)) * 8)];
      }
#pragma unroll
      for (int r = 0; r < 4; ++r)
#pragma unroll
        for (int cb = 0; cb < 2; ++cb)
          acc[r][cb] = __builtin_amdgcn_mfma_f32_16x16x32_bf16(af[r], bfr[cb], acc[r][cb], 0, 0, 0);
    }
  };

  if (fast) {
    for (int ks = 0; ks < 6; ++ks) {
      STAGE(ks * 64);
      __syncthreads();                          // drains vmcnt -> tile landed
      COMPUTE();
      __syncthreads();                          // reads done before next STAGE
    }
  } else {
    // fallback: fp32 input but no bf16 scratch (out buffer too small)
    for (int k0 = 0; k0 < CDIM; k0 += 64) {
#pragma unroll
      for (int i = 0; i < 2; ++i) {
        const int chunk = t + i * 512;
        const int row = chunk >> 3, c8 = chunk & 7;
        const int ldsoff = row * 64 + ((c8 ^ (row & 7)) * 8);
        const float* xp = (const float*)x + (size_t)(m0 + row) * CDIM + k0 + c8 * 8;
        const float4 v0 = *(const float4*)xp;
        const float4 v1 = *(const float4*)(xp + 4);
        *(ushort4*)&Asm[ldsoff]     = make_ushort4(f2bf(v0.x), f2bf(v0.y), f2bf(v0.z), f2bf(v0.w));
        *(ushort4*)&Asm[ldsoff + 4] = make_ushort4(f2bf(v1.x), f2bf(v1.y), f2bf(v1.z), f2bf(v1.w));
        *(uint4*)&Bsm[ldsoff] = *(const uint4*)(W2T + (size_t)(n0 + row) * CDIM + k0 + c8 * 8);
      }
      __syncthreads();
      COMPUTE();
      __syncthreads();
    }
  }

  // ---- epilogue: regs -> LDS [128ch][136] u16 -> coalesced 16B stores ----
  u16* et = smem;                               // 128 x 136 u16 = 34KB
  const int b = m0 >> 14;
  const int TOK0 = m0 & (NTOK - 1);
  const int region = n0 / CDIM;                 // uniform per block (384 = 3*128)
#pragma unroll
  for (int cb = 0; cb < 2; ++cb) {
    const int cl = wc * 32 + cb * 16 + lm;      // local channel 0..127
    const int c = (n0 - region * CDIM) + cl;    // 0..383
    float inv = 1.0f;
    if (region == 0 || region == 2) inv = 1.0f / log1pf(expf(ldx1(scale_p, c, f32)));
#pragma unroll
    for (int r = 0; r < 4; ++r) {
      const int tl = wr * 64 + r * 16 + lq * 4; // local token 0..127
      const f32x4 v = acc[r][cb];
      ushort4 w;
      if (region == 2) {
        const int tok = TOK0 + tl;
        const float p0 = ldx1(pos_enc, (size_t)(tok + 0) * CDIM + c, f32);
        const float p1 = ldx1(pos_enc, (size_t)(tok + 1) * CDIM + c, f32);
        const float p2 = ldx1(pos_enc, (size_t)(tok + 2) * CDIM + c, f32);
        const float p3 = ldx1(pos_enc, (size_t)(tok + 3) * CDIM + c, f32);
        w = make_ushort4(f2bf((v[0] + p0) * inv), f2bf((v[1] + p1) * inv),
                         f2bf((v[2] + p2) * inv), f2bf((v[3] + p3) * inv));
      } else if (region == 0) {
        w = make_ushort4(f2bf(v[0] * inv), f2bf(v[1] * inv), f2bf(v[2] * inv), f2bf(v[3] * inv));
      } else {
        w = make_ushort4(f2bf(v[0]), f2bf(v[1]), f2bf(v[2]), f2bf(v[3]));
      }
      *(ushort4*)&et[cl * 136 + tl] = w;
    }
  }
  __syncthreads();
  u16* dst = (region == 0) ? qsT : (region == 1) ? gT : (region == 2) ? ksT : vT;
  const int cbase = b * CDIM + (n0 - region * CDIM);
#pragma unroll
  for (int i = 0; i < 4; ++i) {
    const int idx = i * 512 + t;
    const int row = idx >> 4, seg = idx & 15;   // row = channel, seg = 16B chunk
    const uint4 val = *(const uint4*)&et[row * 136 + seg * 8];
    *(uint4*)(dst + ((size_t)(cbase + row)) * NTOK + TOK0 + seg * 8) = val;
  }
}

// ---------------- k2: per (b,h): km[96] = mean(kk), kvm[96][48] = kk^T v / N -------
// R15: MFMA. Features bf16 in LDS ([96][72],[48][72]); waves 0-2 own 32-row
// M-slabs x 3 N-tiles: 12 mfma_16x16x32_bf16 + 10 b128 per K=64 tile.
__global__ __launch_bounds__(256) void k2_stats(
    const u16* __restrict__ ksT, const u16* __restrict__ vT,
    const void* __restrict__ power_p, const int* __restrict__ flag,
    float* __restrict__ km, float* __restrict__ kvm)
{
  const bool f32 = (*flag != 0);
  __shared__ __align__(16) u16 kkL[96][72];   // bf16 features (stride 144B, 16B-aligned)
  __shared__ __align__(16) u16 vL[48][72];    // bf16 v
  __shared__ float pw[48];
  const int bh = blockIdx.x;
  const int b = bh >> 3, h = bh & 7;
  const int t = threadIdx.x;
  if (t < 48) pw[t] = 1.0f + 4.0f / (1.0f + expf(-ldx1(power_p, h * HDIM + t, f32)));
  __syncthreads();
  const int wave = t >> 6, lane = t & 63;
  const int lm = lane & 15, lq = lane >> 4;
  f32x4 acc[2][3] = {};                       // waves 0..2: [M-tile][N-tile]
  float ksum = 0.0f;
  const u16* ksbase = ksT + ((size_t)(b * CDIM + h * HDIM)) * NTOK;
  const u16* vbase  = vT  + ((size_t)(b * CDIM + h * HDIM)) * NTOK;
  const int n0base = blockIdx.y * 1024;
  for (int tile = 0; tile < 16; ++tile) {
    const int n0 = n0base + tile * 64;
    for (int i = t; i < 48 * 16; i += 256) {
      const int c = i >> 4, qd = (i & 15) * 4;
      ushort4 kq = *(const ushort4*)(ksbase + (size_t)c * NTOK + n0 + qd);
      ushort4 vq = *(const ushort4*)(vbase  + (size_t)c * NTOK + n0 + qd);
      const float p = pw[c];
      float kf[4] = {bf2f(kq.x), bf2f(kq.y), bf2f(kq.z), bf2f(kq.w)};
      ushort4 pos, neg;
#pragma unroll
      for (int jj = 0; jj < 4; ++jj) {
        const float f = pow_mag(fabsf(kf[jj]), p);
        ((u16*)&pos)[jj] = f2bf((kf[jj] > 0.f) ? f : 0.f);
        ((u16*)&neg)[jj] = f2bf((kf[jj] < 0.f) ? f : 0.f);
      }
      *(ushort4*)&kkL[c][qd]      = pos;
      *(ushort4*)&kkL[c + 48][qd] = neg;
      *(ushort4*)&vL[c][qd]       = vq;       // already bf16
    }
    __syncthreads();
    if (wave < 3) {
      const int mbase = wave * 32;
#pragma unroll
      for (int kh = 0; kh < 2; ++kh) {
        bf16x8 af[2], bfr[3];
#pragma unroll
        for (int mi = 0; mi < 2; ++mi)
          af[mi] = *(const bf16x8*)&kkL[mbase + mi * 16 + lm][kh * 32 + lq * 8];
#pragma unroll
        for (int nj = 0; nj < 3; ++nj)
          bfr[nj] = *(const bf16x8*)&vL[nj * 16 + lm][kh * 32 + lq * 8];
#pragma unroll
        for (int mi = 0; mi < 2; ++mi)
#pragma unroll
          for (int nj = 0; nj < 3; ++nj)
            acc[mi][nj] = __builtin_amdgcn_mfma_f32_16x16x32_bf16(af[mi], bfr[nj], acc[mi][nj], 0, 0, 0);
      }
    }
    if (t < 96) {
#pragma unroll
      for (int nn = 0; nn < 64; nn += 4) {
        const ushort4 kq4 = *(const ushort4*)&kkL[t][nn];
        ksum += (bf2f(kq4.x) + bf2f(kq4.y)) + (bf2f(kq4.z) + bf2f(kq4.w));
      }
    }
    __syncthreads();
  }
  const float inv_n = 1.0f / (float)NTOK;
  if (wave < 3) {
    // C/D layout: col = lane&15 (=e), row = (lane>>4)*4 + reg (=d within tile)
    const int mbase = wave * 32;
#pragma unroll
    for (int mi = 0; mi < 2; ++mi)
#pragma unroll
      for (int nj = 0; nj < 3; ++nj) {
        const f32x4 v = acc[mi][nj];
#pragma unroll
        for (int reg = 0; reg < 4; ++reg) {
          const int d = mbase + mi * 16 + lq * 4 + reg;
          const int e = nj * 16 + lm;
          atomicAdd(&kvm[(size_t)bh * 96 * 48 + d * 48 + e], v[reg] * inv_n);
        }
      }
  }
  if (t < 96) atomicAdd(&km[bh * 96 + t], ksum * inv_n);
}

// ---------------- k3: q features + combined GEMM -> attn (MFMA) --------------------
// R17: one GEMM per (b,h) token-tile: C[96][64] = [kvm | swapped kvm | km |
// swapped km | 0]; out[e<24]=acc[e]/(acc[48]+eps), out[24..47]=acc[e]/(acc[49]+eps).
__global__ __launch_bounds__(256) void k3_attn(
    const u16* __restrict__ qsT, u16* __restrict__ attnT,
    const float* __restrict__ km_g, const float* __restrict__ kvm_g,
    const void* __restrict__ power_p, const int* __restrict__ flag)
{
  const bool f32 = (*flag != 0);
  __shared__ __align__(16) u16 qf[128][104];   // token-major bf16 features (et overlay)
  __shared__ __align__(16) u16 cmat[64][104];  // N-major combined matrix, k contig
  __shared__ float zbuf[4][2][32];
  __shared__ float pw[48];
  const int bh = blockIdx.y;
  const int b = bh >> 3, h = bh & 7;
  const int t = threadIdx.x;
  const int n0 = blockIdx.x * 128;
  if (t < 48) pw[t] = 1.0f + 4.0f / (1.0f + expf(-ldx1(power_p, h * HDIM + t, f32)));
  // build cmat: 64 rows x 96 k (rows 50..63 zero)
  for (int i = t; i < 64 * 96; i += 256) {
    const int nrow = i / 96, d = i - nrow * 96;
    const int ds = (d + 48) % 96;
    float val;
    if (nrow < 24)      val = kvm_g[(size_t)bh * 96 * 48 + d * 48 + nrow];
    else if (nrow < 48) val = kvm_g[(size_t)bh * 96 * 48 + ds * 48 + nrow];
    else if (nrow == 48) val = km_g[bh * 96 + d];
    else if (nrow == 49) val = km_g[bh * 96 + ds];
    else                val = 0.0f;
    cmat[nrow][d] = f2bf(val);
  }
  __syncthreads();                              // pw + cmat ready
  // fill qf: 48 channels x 128 tokens -> features
  const u16* qbase = qsT + ((size_t)(b * CDIM + h * HDIM)) * NTOK + n0;
  for (int i = t; i < 48 * 32; i += 256) {
    const int c = i >> 5, tq = (i & 31) * 4;
    const ushort4 q4 = *(const ushort4*)(qbase + (size_t)c * NTOK + tq);
    const float p = pw[c];
#pragma unroll
    for (int jj = 0; jj < 4; ++jj) {
      const float qv = bf2f(((const u16*)&q4)[jj]);
      const float f = pow_mag(fabsf(qv), p);
      qf[tq + jj][c]      = f2bf((qv > 0.f) ? f : 0.f);
      qf[tq + jj][c + 48] = f2bf((qv < 0.f) ? f : 0.f);
    }
  }
  __syncthreads();
  // MFMA: 4 waves x 32 tokens (2 M-tiles) x N=64 (4 tiles), K=96 (3 steps)
  const int wave = t >> 6, lane = t & 63;
  const int lm = lane & 15, lq = lane >> 4;
  f32x4 acc[2][4] = {};
#pragma unroll
  for (int ks = 0; ks < 3; ++ks) {
    bf16x8 af[2], bfr[4];
#pragma unroll
    for (int mi = 0; mi < 2; ++mi)
      af[mi] = *(const bf16x8*)&qf[wave * 32 + mi * 16 + lm][ks * 32 + lq * 8];
#pragma unroll
    for (int nj = 0; nj < 4; ++nj)
      bfr[nj] = *(const bf16x8*)&cmat[nj * 16 + lm][ks * 32 + lq * 8];
#pragma unroll
    for (int mi = 0; mi < 2; ++mi)
#pragma unroll
      for (int nj = 0; nj < 4; ++nj)
        acc[mi][nj] = __builtin_amdgcn_mfma_f32_16x16x32_bf16(af[mi], bfr[nj], acc[mi][nj], 0, 0, 0);
  }
  // z columns (48,49) -> zbuf[wave][0/1][token]
  if (lm < 2) {
#pragma unroll
    for (int mi = 0; mi < 2; ++mi) {
      const f32x4 v = acc[mi][3];
#pragma unroll
      for (int reg = 0; reg < 4; ++reg)
        zbuf[wave][lm][mi * 16 + lq * 4 + reg] = v[reg];
    }
  }
  __syncthreads();                              // MFMA reads done (qf dead) + zbuf visible
  // epilogue: scale + et overlay -> coalesced stores
  u16* et = &qf[0][0];                          // [48][136] u16 = 13KB < qf
#pragma unroll
  for (int mi = 0; mi < 2; ++mi)
#pragma unroll
    for (int nj = 0; nj < 3; ++nj) {
      const f32x4 v = acc[mi][nj];
      const int e = nj * 16 + lm;
      const int zsel = (e < 24) ? 0 : 1;
#pragma unroll
      for (int reg = 0; reg < 4; ++reg) {
        const int tl = mi * 16 + lq * 4 + reg;  // token within wave slab
        const float z = zbuf[wave][zsel][tl];
        const float zi = 1.0f / (z + 1e-6f);
        et[e * 136 + wave * 32 + tl] = f2bf(v[reg] * zi);
      }
    }
  __syncthreads();
  u16* obase = attnT + ((size_t)(b * CDIM + h * HDIM)) * NTOK + n0;
  for (int i = t; i < 48 * 16; i += 256) {
    const int e = i >> 4, seg = i & 15;
    *(uint4*)(obase + (size_t)e * NTOK + seg * 8) = *(const uint4*)&et[e * 136 + seg * 8];
  }
}

// ---------------- k4: 5x5 depthwise conv on vT + out2 = (attn + conv) * g ----------
// R14: halo baked into tile [20][136] (col = gx+4, zero-padded); 4 outputs per
// thread via 3 aligned float4 reads + register-shifted stencil; ushort4 RMW.
__global__ __launch_bounds__(256) void k4_conv_combine(
    const u16* __restrict__ vT, const u16* __restrict__ gT,
    const void* __restrict__ dwc_w, const void* __restrict__ dwc_b,
    const int* __restrict__ flag,
    u16* __restrict__ attnT)
{
  const bool f32 = (*flag != 0);
  __shared__ float tile[20][136];
  const int bc = blockIdx.y;
  const int y0 = blockIdx.x * 16;
  const int t = threadIdx.x;
  const int d = bc % 48;
  float w[25];
#pragma unroll
  for (int i = 0; i < 25; ++i) w[i] = ldx1(dwc_w, d * 25 + i, f32);
  const float bias = ldx1(dwc_b, d, f32);
  const u16* vimg = vT + (size_t)bc * NTOK;
  for (int i = t; i < 20 * 34; i += 256) {
    const int r = i / 34, cq = (i - r * 34) * 4;   // tile col group (gx = col-4)
    const int gy = y0 + r - 2;
    float4 v4 = make_float4(0.f, 0.f, 0.f, 0.f);
    if (gy >= 0 && gy < IMGH) {
      const int gx0 = cq - 4;
      if (gx0 >= 0 && gx0 + 3 < IMGW) {
        const ushort4 u = *(const ushort4*)(vimg + gy * IMGW + gx0);
        v4 = make_float4(bf2f(u.x), bf2f(u.y), bf2f(u.z), bf2f(u.w));
      } else {
#pragma unroll
        for (int jj = 0; jj < 4; ++jj) {
          const int gx = gx0 + jj;
          ((float*)&v4)[jj] = (gx >= 0 && gx < IMGW) ? bf2f(vimg[gy * IMGW + gx]) : 0.f;
        }
      }
    }
    *(float4*)&tile[r][cq] = v4;
  }
  __syncthreads();
  u16* abase = attnT + (size_t)bc * NTOK;
  const u16* gbase = gT + (size_t)bc * NTOK;
#pragma unroll
  for (int pass = 0; pass < 2; ++pass) {
    const int yy = pass * 8 + (t >> 5);         // 0..15
    const int x0 = (t & 31) * 4;                // 0..124
    float a0 = bias, a1 = bias, a2 = bias, a3 = bias;
#pragma unroll
    for (int dy = 0; dy < 5; ++dy) {
      const float* row = &tile[yy + dy][0];
      const float4 A = *(const float4*)&row[x0];       // gx x0-4..x0-1
      const float4 B = *(const float4*)&row[x0 + 4];   // gx x0..x0+3
      const float4 C = *(const float4*)&row[x0 + 8];   // gx x0+4..x0+7
      const float c0 = A.z, c1 = A.w, c2 = B.x, c3 = B.y,
                  c4 = B.z, c5 = B.w, c6 = C.x, c7 = C.y;
      const float w0 = w[dy * 5 + 0], w1 = w[dy * 5 + 1], w2 = w[dy * 5 + 2],
                  w3 = w[dy * 5 + 3], w4 = w[dy * 5 + 4];
      a0 = fmaf(w0, c0, fmaf(w1, c1, fmaf(w2, c2, fmaf(w3, c3, fmaf(w4, c4, a0)))));
      a1 = fmaf(w0, c1, fmaf(w1, c2, fmaf(w2, c3, fmaf(w3, c4, fmaf(w4, c5, a1)))));
      a2 = fmaf(w0, c2, fmaf(w1, c3, fmaf(w2, c4, fmaf(w3, c5, fmaf(w4, c6, a2)))));
      a3 = fmaf(w0, c3, fmaf(w1, c4, fmaf(w2, c5, fmaf(w3, c6, fmaf(w4, c7, a3)))));
    }
    const int gidx = (y0 + yy) * IMGW + x0;
    const ushort4 at = *(const ushort4*)(abase + gidx);
    const ushort4 gg = *(const ushort4*)(gbase + gidx);
    *(ushort4*)(abase + gidx) = make_ushort4(
        f2bf((bf2f(at.x) + a0) * bf2f(gg.x)),
        f2bf((bf2f(at.y) + a1) * bf2f(gg.y)),
        f2bf((bf2f(at.z) + a2) * bf2f(gg.z)),
        f2bf((bf2f(at.w) + a3) * bf2f(gg.w)));
  }
}

// ---------------- k4b: transpose out2 channel-major -> token-major -----------------
__global__ __launch_bounds__(256) void k4b_transpose(
    const u16* __restrict__ src,   // [(b*384+c)][n]
    u16* __restrict__ dst)         // [(b*16384+n)][c]
{
  __shared__ u16 tile[64][68];
  const int b  = blockIdx.z;
  const int c0 = blockIdx.y * 64;
  const int n0 = blockIdx.x * 64;
  const int t = threadIdx.x;
  const int tr = t >> 4, tq = t & 15;
#pragma unroll
  for (int i = 0; i < 4; ++i) {
    const int r = tr + i * 16;     // c-row
    *(ushort4*)&tile[r][tq * 4] =
        *(const ushort4*)(src + ((size_t)(b * CDIM + c0 + r)) * NTOK + n0 + tq * 4);
  }
  __syncthreads();
#pragma unroll
  for (int i = 0; i < 4; ++i) {
    const int n = tr + i * 16;     // token-row
    const ushort4 vv = make_ushort4(tile[tq * 4 + 0][n], tile[tq * 4 + 1][n],
                                    tile[tq * 4 + 2][n], tile[tq * 4 + 3][n]);
    *(ushort4*)(dst + ((size_t)(b * NTOK + n0 + n)) * CDIM + c0 + tq * 4) = vv;
  }
}

// ---------------- k5: MFMA GEMM out2_tm @ Wproj + b -> d_out -----------------------
// R16: k1's recipe. 512 thr / 8 waves (2M x 4N, acc[4][2]); single 32KB
// staging; 34KB union; fp32 epilogue 2-pass ef[64][132], 512B row stores.
__global__ __launch_bounds__(512) void k5_mfma(
    const u16* __restrict__ A,     // [row=b*16384+n][c] bf16
    const u16* __restrict__ WpT,   // [c_out][c_in] bf16
    const void* __restrict__ bp, const int* __restrict__ flag,
    void* __restrict__ out)
{
  const bool f32 = (*flag != 0);
  __shared__ __align__(16) u16 smem[17408];
  u16* Asm = smem;
  u16* Bsm = smem + 8192;
  const int t = threadIdx.x;
  const int bid = blockIdx.x;                   // 0..1535
  const int rm = (bid & 7) * 192 + (bid >> 3);  // XCD-contiguous remap
  const int m_idx = rm / 3;
  const int n_idx = rm - m_idx * 3;
  const int n0 = n_idx * 128;                   // 0..383
  const int m0 = m_idx * 128;
  const int wave = t >> 6, lane = t & 63;
  const int wr = wave >> 2, wc = wave & 3;      // 2M x 4N
  const int lm = lane & 15, lq = lane >> 4;

  f32x4 acc[4][2] = {};

  auto STAGE = [&](int k0) {
#pragma unroll
    for (int i = 0; i < 2; ++i) {
      const int chunk = i * 512 + t;
      const int row = chunk >> 3, c8 = chunk & 7;
      const int sc8 = c8 ^ (row & 7);           // source-side swizzle
      u16* lpA = &Asm[(i * 512 + wave * 64) * 8];
      u16* lpB = &Bsm[(i * 512 + wave * 64) * 8];
      gload16(lpA, A + (size_t)(m0 + row) * CDIM + k0 + sc8 * 8);
      gload16(lpB, WpT + (size_t)(n0 + row) * CDIM + k0 + sc8 * 8);
    }
  };
  auto COMPUTE = [&]() {
#pragma unroll
    for (int kh = 0; kh < 2; ++kh) {
      bf16x8 af[4], bfr[2];
#pragma unroll
      for (int r = 0; r < 4; ++r) {
        const int row = wr * 64 + r * 16 + lm;
        af[r] = *(const bf16x8*)&Asm[row * 64 + (((kh * 4 + lq) ^ (row & 7)) * 8)];
      }
#pragma unroll
      for (int cb = 0; cb < 2; ++cb) {
        const int row = wc * 32 + cb * 16 + lm;
        bfr[cb] = *(const bf16x8*)&Bsm[row * 64 + (((kh * 4 + lq) ^ (row & 7)) * 8)];
      }
#pragma unroll
      for (int r = 0; r < 4; ++r)
#pragma unroll
        for (int cb = 0; cb < 2; ++cb)
          acc[r][cb] = __builtin_amdgcn_mfma_f32_16x16x32_bf16(af[r], bfr[cb], acc[r][cb], 0, 0, 0);
    }
  };

  for (int ks = 0; ks < 6; ++ks) {
    STAGE(ks * 64);
    __syncthreads();
    COMPUTE();
    __syncthreads();
  }

  if (f32) {
    // ---- coalesced fp32 epilogue: 2 half-tile passes through LDS ----
    float* ef = (float*)smem;                   // 64 x 132 f32 = 33.8KB
    float bb[2];
#pragma unroll
    for (int cb = 0; cb < 2; ++cb) bb[cb] = ((const float*)bp)[n0 + wc * 32 + cb * 16 + lm];
    for (int h = 0; h < 2; ++h) {
      __syncthreads();                          // K-loop reads / prev pass done
      if (wr == h) {
#pragma unroll
        for (int cb = 0; cb < 2; ++cb) {
          const int cl = wc * 32 + cb * 16 + lm;    // 0..127
#pragma unroll
          for (int r = 0; r < 4; ++r) {
            const int tl = r * 16 + lq * 4;         // 0..63 in half-tile
            const f32x4 v = acc[r][cb];
#pragma unroll
            for (int reg = 0; reg < 4; ++reg)
              ef[(tl + reg) * 132 + cl] = v[reg] + bb[cb];
          }
        }
      }
      __syncthreads();
      // store 64 rows x 128 c: 512B contiguous per row
      float* ob = (float*)out + (size_t)(m0 + h * 64) * CDIM + n0;
#pragma unroll
      for (int i = 0; i < 4; ++i) {
        const int idx = i * 512 + t;
        const int row = idx >> 5, seg = idx & 31; // 32 x float4 per row
        const float4 val = *(const float4*)&ef[row * 132 + seg * 4];
        *(float4*)(ob + (size_t)row * CDIM + seg * 4) = val;
      }
    }
  } else {
    // bf16 out: scattered path (rare)
#pragma unroll
    for (int cb = 0; cb < 2; ++cb) {
      const int cg = n0 + wc * 32 + cb * 16 + lm;
      const float bbs = bf2f(((const u16*)bp)[cg]);
#pragma unroll
      for (int r = 0; r < 4; ++r) {
        const int rowtok = m0 + wr * 64 + r * 16 + lq * 4;
        const f32x4 v = acc[r][cb];
#pragma unroll
        for (int reg = 0; reg < 4; ++reg) {
          const size_t o = (size_t)(rowtok + reg) * CDIM + cg;
          ((u16*)out)[o] = f2bf(v[reg] + bbs);
        }
      }
    }
  }
}

extern "C" void kernel_launch(void* const* d_in, const int* in_sizes, int n_in,
                              void* d_out, int out_size, void* d_ws, size_t ws_size,
                              hipStream_t stream) {
  const void* x       = d_in[0];
  const void* Wqg     = d_in[1];
  const void* Wkv     = d_in[2];
  const void* Wproj   = d_in[3];
  const void* bproj   = d_in[4];
  const void* pos_enc = d_in[5];
  const void* power_p = d_in[6];
  const void* scale_p = d_in[7];
  const void* dwc_w   = d_in[8];
  const void* dwc_b   = d_in[9];

  const size_t S = (size_t)NB * NTOK * CDIM;                 // 25,165,824
  const size_t stats_off   = 256;
  const size_t stats_bytes = (size_t)(32 * 96 + 32 * 96 * 48) * sizeof(float);
  const size_t w2t_elems = 1536 * 384, wpt_elems = 384 * 384;
  const size_t need = stats_off + stats_bytes + 3 * S * sizeof(u16)
                    + (w2t_elems + wpt_elems) * sizeof(u16);
  if (ws_size < need) return;

  int*   flag = (int*)d_ws;
  float* km   = (float*)((char*)d_ws + stats_off);
  float* kvm  = km + 32 * 96;
  u16* qsT = (u16*)((char*)d_ws + stats_off + stats_bytes);  // q/scale; later out2_tm
  u16* gT  = qsT + S;
  u16* ksT = gT + S;                                         // k feats; attn; out2
  u16* W2T = ksT + S;
  u16* WpT = W2T + w2t_elems;
  u16* vT  = (u16*)d_out;                                    // dead before k5 writes

  // bf16 scratch for x lives in the SECOND half of d_out when out is fp32
  // (bytes [2S, 4S) -- disjoint from vT's [0, 2S); dead once k1 completes,
  // k5 overwrites the whole out buffer afterwards).
  const int conv_ok = (out_size >= (int)(S * 4)) ? 1 : 0;
  u16* xbf = conv_ok ? ((u16*)d_out + S) : (u16*)d_out;      // unused if !conv_ok

  hipMemsetAsync(km, 0, stats_bytes, stream);

  k0_detect<<<1, 256, 0, stream>>>(x, flag);
  if (conv_ok) kx_convert<<<2048, 256, 0, stream>>>(x, flag, xbf);
  kprep<<<(int)((w2t_elems + wpt_elems + 255) / 256), 256, 0, stream>>>(
      Wqg, Wkv, Wproj, flag, W2T, WpT);
  k1_mfma<<<6144, 512, 0, stream>>>(x, xbf, W2T, pos_enc, scale_p, flag, conv_ok,
                                    qsT, gT, ksT, vT);
  k2_stats<<<dim3(32, 16), 256, 0, stream>>>(ksT, vT, power_p, flag, km, kvm);
  k3_attn<<<dim3(128, 32), 256, 0, stream>>>(qsT, ksT, km, kvm, power_p, flag);
  k4_conv_combine<<<dim3(8, 1536), 256, 0, stream>>>(vT, gT, dwc_w, dwc_b, flag, ksT);
  k4b_transpose<<<dim3(256, 6, 4), 256, 0, stream>>>(ksT, qsT);
  k5_mfma<<<1536, 512, 0, stream>>>(qsT, WpT, bproj, flag, d_out);
}